// Round 1
// baseline (3054.257 us; speedup 1.0000x reference)
//
#include <hip/hip_runtime.h>
#include <math.h>

// ---- problem constants ----
#define Bb 32
#define DFc 8
#define Hh 144
#define Ww 144
#define OFFc 2
#define KWc 5
#define DSc 512
#define DTc 1024
#define NCc 6
#define HEADSc 16
#define DHc 64
#define MLPc 2048
#define CINc (DFc * Ww)        // 1152
#define ITCc (DFc * Hh * KWc)  // 5760
#define BHc (Bb * Hh)          // 4608
#define INNERc (HEADSc * DHc)  // 1024
#define EPSc 1e-5f
#define THRc 0.3f

// ============================================================
// NN GEMM: C[M x N] = A[M x K] (row-major, lda=K) @ B[K x N] (row-major, ldb=N)
// epilogue: C = dot*scale[row] + shift[z*shiftStride + row]  (scale/shift nullable)
// 128x128 tile, BK=16, 256 threads, 8x8 microtile (split 4+4).
// Requires N%128==0, K%16==0. M guarded.
// ============================================================
__global__ __launch_bounds__(256) void gemm_nn(
    const float* __restrict__ A, const float* __restrict__ Bm, float* __restrict__ C,
    int M, int N, int K,
    long batchA, long batchB, long batchC,
    const float* __restrict__ scale, const float* __restrict__ shift, int shiftStride)
{
    __shared__ float As[16][132];
    __shared__ float Bs[16][132];
    const int tid = threadIdx.x;
    const int z = blockIdx.z;
    A += z * batchA; Bm += z * batchB; C += z * batchC;
    const int n0 = blockIdx.x * 128;
    const int m0 = blockIdx.y * 128;
    const int aRow = tid >> 2, aCol = (tid & 3) << 2;
    const int bRow = tid >> 5, bCol = (tid & 31) << 2;
    const int ty = tid >> 4, tx = tid & 15;

    float acc[8][8];
#pragma unroll
    for (int i = 0; i < 8; i++)
#pragma unroll
        for (int j = 0; j < 8; j++) acc[i][j] = 0.f;

    for (int k0 = 0; k0 < K; k0 += 16) {
#pragma unroll
        for (int r = 0; r < 2; r++) {
            int row = m0 + aRow + r * 64;
            float4 av = make_float4(0.f, 0.f, 0.f, 0.f);
            if (row < M) av = *(const float4*)(A + (long)row * K + k0 + aCol);
            As[aCol + 0][aRow + r * 64] = av.x;
            As[aCol + 1][aRow + r * 64] = av.y;
            As[aCol + 2][aRow + r * 64] = av.z;
            As[aCol + 3][aRow + r * 64] = av.w;
        }
#pragma unroll
        for (int r = 0; r < 2; r++) {
            int krow = k0 + bRow + r * 8;
            float4 bv = *(const float4*)(Bm + (long)krow * N + n0 + bCol);
            *(float4*)&Bs[bRow + r * 8][bCol] = bv;
        }
        __syncthreads();
#pragma unroll
        for (int kk = 0; kk < 16; kk++) {
            float4 a0 = *(const float4*)&As[kk][ty * 4];
            float4 a1 = *(const float4*)&As[kk][64 + ty * 4];
            float4 b0 = *(const float4*)&Bs[kk][tx * 4];
            float4 b1 = *(const float4*)&Bs[kk][64 + tx * 4];
            float a[8] = {a0.x, a0.y, a0.z, a0.w, a1.x, a1.y, a1.z, a1.w};
            float b[8] = {b0.x, b0.y, b0.z, b0.w, b1.x, b1.y, b1.z, b1.w};
#pragma unroll
            for (int i = 0; i < 8; i++)
#pragma unroll
                for (int j = 0; j < 8; j++) acc[i][j] += a[i] * b[j];
        }
        __syncthreads();
    }
#pragma unroll
    for (int gi = 0; gi < 2; gi++) {
#pragma unroll
        for (int i = 0; i < 4; i++) {
            int row = m0 + gi * 64 + ty * 4 + i;
            if (row >= M) continue;
            float sc = scale ? scale[row] : 1.f;
            float sh = shift ? shift[(long)z * shiftStride + row] : 0.f;
#pragma unroll
            for (int gj = 0; gj < 2; gj++) {
                float4 o;
                o.x = acc[gi * 4 + i][gj * 4 + 0] * sc + sh;
                o.y = acc[gi * 4 + i][gj * 4 + 1] * sc + sh;
                o.z = acc[gi * 4 + i][gj * 4 + 2] * sc + sh;
                o.w = acc[gi * 4 + i][gj * 4 + 3] * sc + sh;
                *(float4*)(C + (long)row * N + n0 + gj * 64 + tx * 4) = o;
            }
        }
    }
}

// ============================================================
// NT GEMM: C[M x N] = A[M x K] (row-major) @ B[N x K]^T (row-major)
// epilogue: + bias[n] (nullable), optional accumulate into C.
// 64x64 tile, BK=16, 256 threads, 4x4 microtile.
// Requires M%64==0, N%64==0, K%16==0.
// ============================================================
__global__ __launch_bounds__(256) void gemm_nt(
    const float* __restrict__ A, const float* __restrict__ Bm, float* __restrict__ C,
    int M, int N, int K, const float* __restrict__ bias, int accumulate)
{
    __shared__ float As[16][68];
    __shared__ float Bs[16][68];
    const int tid = threadIdx.x;
    const int n0 = blockIdx.x * 64;
    const int m0 = blockIdx.y * 64;
    const int lRow = tid >> 2, lCol = (tid & 3) << 2;
    const int ty = tid >> 4, tx = tid & 15;

    float acc[4][4];
#pragma unroll
    for (int i = 0; i < 4; i++)
#pragma unroll
        for (int j = 0; j < 4; j++) acc[i][j] = 0.f;

    for (int k0 = 0; k0 < K; k0 += 16) {
        float4 av = *(const float4*)(A + (long)(m0 + lRow) * K + k0 + lCol);
        As[lCol + 0][lRow] = av.x; As[lCol + 1][lRow] = av.y;
        As[lCol + 2][lRow] = av.z; As[lCol + 3][lRow] = av.w;
        float4 bv = *(const float4*)(Bm + (long)(n0 + lRow) * K + k0 + lCol);
        Bs[lCol + 0][lRow] = bv.x; Bs[lCol + 1][lRow] = bv.y;
        Bs[lCol + 2][lRow] = bv.z; Bs[lCol + 3][lRow] = bv.w;
        __syncthreads();
#pragma unroll
        for (int kk = 0; kk < 16; kk++) {
            float4 a = *(const float4*)&As[kk][ty * 4];
            float4 b = *(const float4*)&Bs[kk][tx * 4];
            float aa[4] = {a.x, a.y, a.z, a.w};
            float bb[4] = {b.x, b.y, b.z, b.w};
#pragma unroll
            for (int i = 0; i < 4; i++)
#pragma unroll
                for (int j = 0; j < 4; j++) acc[i][j] += aa[i] * bb[j];
        }
        __syncthreads();
    }
    const int ncol = n0 + tx * 4;
    float4 bv = make_float4(0.f, 0.f, 0.f, 0.f);
    if (bias) bv = *(const float4*)(bias + ncol);
#pragma unroll
    for (int i = 0; i < 4; i++) {
        int row = m0 + ty * 4 + i;
        float4 o = make_float4(acc[i][0] + bv.x, acc[i][1] + bv.y,
                               acc[i][2] + bv.z, acc[i][3] + bv.w);
        float* cp = C + (long)row * N + ncol;
        if (accumulate) {
            float4 pv = *(const float4*)cp;
            o.x += pv.x; o.y += pv.y; o.z += pv.z; o.w += pv.w;
        }
        *(float4*)cp = o;
    }
}

// ============================================================
// transpose x(B,DF,H,W) -> Xb[(f*W+w)*BH + b*H+h]
// ============================================================
__global__ void k_transpose(const float* __restrict__ x, float* __restrict__ Xb)
{
    __shared__ float tile[32][33];
    const int bf = blockIdx.z;
    const int b = bf >> 3, f = bf & 7;
    const int w0 = blockIdx.x * 32, h0 = blockIdx.y * 32;
    const int tx = threadIdx.x, ty = threadIdx.y;  // (32,8)
    const float* xp = x + (long)(b * DFc + f) * Hh * Ww;
#pragma unroll
    for (int i = 0; i < 4; i++) {
        int h = h0 + ty + i * 8, w = w0 + tx;
        float v = (h < Hh && w < Ww) ? xp[h * Ww + w] : 0.f;
        tile[ty + i * 8][tx] = v;
    }
    __syncthreads();
#pragma unroll
    for (int i = 0; i < 4; i++) {
        int w = w0 + ty + i * 8, h = h0 + tx;
        if (w < Ww && h < Hh)
            Xb[(long)(f * Ww + w) * BHc + b * Hh + h] = tile[tx][ty + i * 8];
    }
}

// scale = g*rsqrt(vr+eps); shift = (b1-mu)*scale + bt
__global__ void k_scale_shift(const float* __restrict__ g, const float* __restrict__ vr,
                              const float* __restrict__ mu, const float* __restrict__ bt,
                              const float* __restrict__ b1,
                              float* __restrict__ scale, float* __restrict__ shift, int n)
{
    int i = blockIdx.x * 256 + threadIdx.x;
    if (i >= n) return;
    float sc = g[i] * rsqrtf(vr[i] + EPSc);
    scale[i] = sc;
    shift[i] = (b1[i] - mu[i]) * sc + bt[i];
}

// ext head: logits (O=2) + softmax + exist reduction. block per (b,nc).
__global__ __launch_bounds__(256) void k_ext_head(
    const float* __restrict__ hbuf, const float* __restrict__ w2, const float* __restrict__ b2,
    float* __restrict__ outExt, int* __restrict__ exist)
{
    __shared__ float red[256];
    const int bc = blockIdx.x;
    const int b = bc / NCc, nc = bc % NCc;
    const int h = threadIdx.x;
    float p0 = 0.f;
    if (h < Hh) {
        const int col = b * Hh + h;
        const float* hp = hbuf + (long)(nc * DSc) * BHc + col;
        const float* w0p = w2 + (nc * 2 + 0) * DSc;
        const float* w1p = w2 + (nc * 2 + 1) * DSc;
        float lg0 = b2[nc * 2 + 0], lg1 = b2[nc * 2 + 1];
        for (int s = 0; s < DSc; s++) {
            float hv = hp[(long)s * BHc];
            lg0 += hv * w0p[s];
            lg1 += hv * w1p[s];
        }
        float mx = fmaxf(lg0, lg1);
        float e0 = expf(lg0 - mx), e1 = expf(lg1 - mx);
        float inv = 1.f / (e0 + e1);
        p0 = e0 * inv;
        float* op = outExt + ((long)bc * Hh + h) * 2;
        op[0] = p0;
        op[1] = e1 * inv;
    }
    red[threadIdx.x] = p0;
    __syncthreads();
    for (int st = 128; st > 0; st >>= 1) {
        if (threadIdx.x < st) red[threadIdx.x] += red[threadIdx.x + st];
        __syncthreads();
    }
    if (threadIdx.x == 0) exist[bc] = (red[0] / Hh > THRc) ? 1 : 0;
}

// cls softmax + argmax: one thread per (nc, col=b*H+h)
__global__ void k_cls_softmax(const float* __restrict__ lg, float* __restrict__ outCls,
                              int* __restrict__ corr)
{
    int tid = blockIdx.x * 256 + threadIdx.x;
    if (tid >= NCc * BHc) return;
    int nc = tid / BHc, col = tid % BHc;
    int b = col / Hh, h = col % Hh;
    const float* p = lg + (long)nc * Ww * BHc + col;
    float mx = -1e30f;
    int bi = 0;
    for (int o = 0; o < Ww; o++) {
        float v = p[(long)o * BHc];
        if (v > mx) { mx = v; bi = o; }
    }
    float sum = 0.f;
    for (int o = 0; o < Ww; o++) sum += expf(p[(long)o * BHc] - mx);
    float inv = 1.f / sum;
    float* op = outCls + ((long)(b * NCc + nc) * Hh + h) * Ww;
    for (int o = 0; o < Ww; o++) op[o] = expf(p[(long)o * BHc] - mx) * inv;
    corr[(b * NCc + nc) * Hh + h] = bi;
}

// gather window: win[(b*NC+nc)][f*H*K + h*K + k]
__global__ void k_gather(const float* __restrict__ x, const int* __restrict__ corr,
                         float* __restrict__ win)
{
    int tid = blockIdx.x * 256 + threadIdx.x;
    if (tid >= Bb * NCc * ITCc) return;
    int row = tid / ITCc, i = tid % ITCc;
    int b = row / NCc, nc = row % NCc;
    int f = i / (Hh * KWc);
    int r = i % (Hh * KWc);
    int h = r / KWc, k = r % KWc;
    int j = corr[(b * NCc + nc) * Hh + h] + k - OFFc;
    float v = 0.f;
    if (j >= 0 && j < Ww) v = x[((long)(b * DFc + f) * Hh + h) * Ww + j];
    win[tid] = v;
}

__global__ void k_add_emb(float* __restrict__ tok, const float* __restrict__ emb)
{
    int tid = blockIdx.x * 256 + threadIdx.x;
    if (tid >= Bb * NCc * DTc) return;
    int row = tid / DTc, n = tid % DTc;
    tok[tid] += emb[(row % NCc) * DTc + n];
}

__global__ __launch_bounds__(256) void k_layernorm(
    const float* __restrict__ in, const float* __restrict__ g,
    const float* __restrict__ bta, float* __restrict__ out)
{
    __shared__ float r1[256], r2[256];
    const int row = blockIdx.x;
    const int t = threadIdx.x;
    const float* p = in + (long)row * DTc;
    float s = 0.f, sq = 0.f;
    for (int i = t; i < DTc; i += 256) {
        float v = p[i];
        s += v; sq += v * v;
    }
    r1[t] = s; r2[t] = sq;
    __syncthreads();
    for (int st = 128; st > 0; st >>= 1) {
        if (t < st) { r1[t] += r1[t + st]; r2[t] += r2[t + st]; }
        __syncthreads();
    }
    float mean = r1[0] / DTc;
    float var = r2[0] / DTc - mean * mean;
    float rstd = rsqrtf(var + EPSc);
    float* o = out + (long)row * DTc;
    for (int i = t; i < DTc; i += 256) o[i] = (p[i] - mean) * rstd * g[i] + bta[i];
}

// tiny attention: one thread per (b, head, n)
__global__ void k_attention(const float* __restrict__ qkv, const int* __restrict__ exist,
                            float* __restrict__ obuf)
{
    int idx = blockIdx.x * 256 + threadIdx.x;
    if (idx >= Bb * HEADSc * NCc) return;
    int b = idx / (HEADSc * NCc);
    int r = idx % (HEADSc * NCc);
    int hd = r / NCc, n = r % NCc;
    const float* base = qkv + (long)b * NCc * (3 * INNERc);
    const float* q = base + (long)n * (3 * INNERc) + hd * DHc;
    float s[NCc];
    for (int m = 0; m < NCc; m++) {
        const float* kp = base + (long)m * (3 * INNERc) + INNERc + hd * DHc;
        float d = 0.f;
        for (int t = 0; t < DHc; t++) d += q[t] * kp[t];
        s[m] = exist[b * NCc + m] ? d * 0.125f : -1e9f;
    }
    float mx = s[0];
    for (int m = 1; m < NCc; m++) mx = fmaxf(mx, s[m]);
    float sum = 0.f;
    for (int m = 0; m < NCc; m++) { s[m] = expf(s[m] - mx); sum += s[m]; }
    float inv = 1.f / sum;
    for (int m = 0; m < NCc; m++) s[m] *= inv;
    float* op = obuf + (long)(b * NCc + n) * INNERc + hd * DHc;
    for (int t = 0; t < DHc; t++) {
        float acc = 0.f;
        for (int m = 0; m < NCc; m++)
            acc += s[m] * base[(long)m * (3 * INNERc) + 2 * INNERc + hd * DHc + t];
        op[t] = acc;
    }
}

__global__ void k_gelu(float* __restrict__ p, int n)
{
    int tid = blockIdx.x * 256 + threadIdx.x;
    if (tid < n) {
        float v = p[tid];
        p[tid] = 0.5f * v * (1.f + erff(v * 0.70710678118654752440f));
    }
}

__global__ void k_copy4(const float4* __restrict__ s, float4* __restrict__ d, int n)
{
    int tid = blockIdx.x * 256 + threadIdx.x;
    if (tid < n) d[tid] = s[tid];
}

// scatter dec into x2; per-(b,h,f) thread, c descending, first-writer-wins per column
// (== reference's sequential c-ascending last-writer-wins).
__global__ void k_scatter(const float* __restrict__ dec, const int* __restrict__ corr,
                          const int* __restrict__ exist, float* __restrict__ x2)
{
    int idx = blockIdx.x * 256 + threadIdx.x;
    if (idx >= Bb * Hh * DFc) return;
    int b = idx / (Hh * DFc);
    int r = idx % (Hh * DFc);
    int h = r / DFc, f = r % DFc;
    if (h >= Hh - 1) return;  // hmask
    unsigned long long m0 = 0ull, m1 = 0ull, m2 = 0ull;
    float* xrow = x2 + ((long)(b * DFc + f) * Hh + h) * Ww;
    for (int c = NCc - 1; c >= 0; c--) {
        if (!exist[b * NCc + c]) continue;
        int cr = corr[(b * NCc + c) * Hh + h];
        const float* dp = dec + (long)(b * NCc + c) * ITCc + f * (Hh * KWc) + h * KWc;
        for (int k = 0; k < KWc; k++) {
            int j = cr + k - OFFc;
            if (j < 0 || j >= Ww) continue;
            bool seen;
            if (j < 64) { unsigned long long bit = 1ull << j; seen = (m0 & bit) != 0; m0 |= bit; }
            else if (j < 128) { unsigned long long bit = 1ull << (j - 64); seen = (m1 & bit) != 0; m1 |= bit; }
            else { unsigned long long bit = 1ull << (j - 128); seen = (m2 & bit) != 0; m2 |= bit; }
            if (!seen) xrow[j] = dp[k];
        }
    }
}

extern "C" void kernel_launch(void* const* d_in, const int* in_sizes, int n_in,
                              void* d_out, int out_size, void* d_ws, size_t ws_size,
                              hipStream_t stream)
{
    const float* const* in = (const float* const*)d_in;
    const float* x = in[0];
    // input index bases: ext=1, cls=9, ext2=17, cls2=25
    // per head: +0 w1, +1 b1, +2 g, +3 bt, +4 mu, +5 vr, +6 w2, +7 b2
    const float* emb = in[33];
    const float* tok_w = in[34]; const float* tok_b = in[35];
    const float* ln1_g = in[36]; const float* ln1_b = in[37];
    const float* qkv_w = in[38];
    const float* out_w = in[39]; const float* out_b = in[40];
    const float* ln2_g = in[41]; const float* ln2_b = in[42];
    const float* ff_w1 = in[43]; const float* ff_b1 = in[44];
    const float* ff_w2 = in[45]; const float* ff_b2 = in[46];
    const float* lnf_g = in[47]; const float* lnf_b = in[48];
    const float* dec_w = in[49]; const float* dec_b = in[50];

    float* out = (float*)d_out;
    float* outExt1 = out;                                  // 32*6*144*2   = 55296
    float* outCls1 = out + 55296;                          // 32*6*144*144 = 3981312
    float* outExt2 = out + 4036608;
    float* outCls2 = out + 4091904;

    // ---- workspace layout (floats), with deliberate aliasing ----
    float* ws = (float*)d_ws;
    float* Xb    = ws;                  // 5,308,416  (CIN x BH); aliased by clslg
    float* hbuf  = ws + 5308416;        // 14,155,776 (3072 x BH); first 5.3M aliased by x2
    float* windec = ws + 19464192;      // 1,105,920  (win, later dec)
    float* tok   = ws + 20570112;       // 196,608
    float* ybuf  = ws + 20766720;       // 196,608
    float* qkvB  = ws + 20963328;       // 589,824
    float* obuf  = ws + 21553152;       // 196,608
    float* ffh   = ws + 21749760;       // 393,216
    float* scaleB = ws + 22142976;      // 3072
    float* shiftB = ws + 22146048;      // 3072
    int* corrB  = (int*)(ws + 22149120); // 27648
    int* existB = corrB + 27648;         // 192
    float* clslg = Xb;                   // alias: 6*144*4608 = 3,981,312 <= Xb size
    float* x2    = hbuf;                 // alias: 5,308,416 <= hbuf size
    float* win = windec;
    float* dec = windec;

    auto run_heads = [&](int be, int bc, float* oExt, float* oCls) {
        // ext head
        k_scale_shift<<<12, 256, 0, stream>>>(in[be + 2], in[be + 5], in[be + 4],
                                              in[be + 3], in[be + 1], scaleB, shiftB, NCc * DSc);
        gemm_nn<<<dim3(36, 24, 1), 256, 0, stream>>>(in[be + 0], Xb, hbuf,
                                                     NCc * DSc, BHc, CINc, 0, 0, 0,
                                                     scaleB, shiftB, 0);
        k_ext_head<<<Bb * NCc, 256, 0, stream>>>(hbuf, in[be + 6], in[be + 7], oExt, existB);
        // cls head
        k_scale_shift<<<12, 256, 0, stream>>>(in[bc + 2], in[bc + 5], in[bc + 4],
                                              in[bc + 3], in[bc + 1], scaleB, shiftB, NCc * DSc);
        gemm_nn<<<dim3(36, 24, 1), 256, 0, stream>>>(in[bc + 0], Xb, hbuf,
                                                     NCc * DSc, BHc, CINc, 0, 0, 0,
                                                     scaleB, shiftB, 0);
        // batched over nc: lg[nc] = cls_w2[nc] (144x512) @ hbuf[nc*512..] (512xBH) + b2
        gemm_nn<<<dim3(36, 2, NCc), 256, 0, stream>>>(in[bc + 6], hbuf, clslg,
                                                      Ww, BHc, DSc,
                                                      (long)Ww * DSc, (long)DSc * BHc, (long)Ww * BHc,
                                                      nullptr, in[bc + 7], Ww);
        k_cls_softmax<<<108, 256, 0, stream>>>(clslg, oCls, corrB);
    };

    // ======== stage 1 ========
    k_transpose<<<dim3(5, 5, Bb * DFc), dim3(32, 8), 0, stream>>>(x, Xb);
    run_heads(1, 9, outExt1, outCls1);

    // gather + token projection
    k_gather<<<4320, 256, 0, stream>>>(x, corrB, win);
    gemm_nt<<<dim3(16, 3), 256, 0, stream>>>(win, tok_w, tok, 192, DTc, ITCc, tok_b, 0);
    k_add_emb<<<768, 256, 0, stream>>>(tok, emb);

    // transformer block
    k_layernorm<<<192, 256, 0, stream>>>(tok, ln1_g, ln1_b, ybuf);
    gemm_nt<<<dim3(48, 3), 256, 0, stream>>>(ybuf, qkv_w, qkvB, 192, 3 * INNERc, DTc, nullptr, 0);
    k_attention<<<12, 256, 0, stream>>>(qkvB, existB, obuf);
    gemm_nt<<<dim3(16, 3), 256, 0, stream>>>(obuf, out_w, tok, 192, DTc, INNERc, out_b, 1);
    k_layernorm<<<192, 256, 0, stream>>>(tok, ln2_g, ln2_b, ybuf);
    gemm_nt<<<dim3(32, 3), 256, 0, stream>>>(ybuf, ff_w1, ffh, 192, MLPc, DTc, ff_b1, 0);
    k_gelu<<<1536, 256, 0, stream>>>(ffh, 192 * MLPc);
    gemm_nt<<<dim3(16, 3), 256, 0, stream>>>(ffh, ff_w2, tok, 192, DTc, MLPc, ff_b2, 1);
    k_layernorm<<<192, 256, 0, stream>>>(tok, lnf_g, lnf_b, ybuf);
    gemm_nt<<<dim3(90, 3), 256, 0, stream>>>(ybuf, dec_w, dec, 192, ITCc, DTc, dec_b, 0);

    // scatter into x2 (copy of x)
    k_copy4<<<5184, 256, 0, stream>>>((const float4*)x, (float4*)x2, 1327104);
    k_scatter<<<144, 256, 0, stream>>>(dec, corrB, existB, x2);

    // ======== stage 2 ========
    k_transpose<<<dim3(5, 5, Bb * DFc), dim3(32, 8), 0, stream>>>(x2, Xb);
    run_heads(17, 25, outExt2, outCls2);

    (void)in_sizes; (void)n_in; (void)out_size; (void)ws_size;
}

// Round 2
// 1871.208 us; speedup vs baseline: 1.6322x; 1.6322x over previous
//
#include <hip/hip_runtime.h>
#include <math.h>

// ---- problem constants ----
#define Bb 32
#define DFc 8
#define Hh 144
#define Ww 144
#define OFFc 2
#define KWc 5
#define DSc 512
#define DTc 1024
#define NCc 6
#define HEADSc 16
#define DHc 64
#define MLPc 2048
#define CINc (DFc * Ww)        // 1152
#define ITCc (DFc * Hh * KWc)  // 5760
#define BHc (Bb * Hh)          // 4608
#define INNERc (HEADSc * DHc)  // 1024
#define EPSc 1e-5f
#define THRc 0.3f

typedef __attribute__((ext_vector_type(8))) short short8;
typedef __attribute__((ext_vector_type(4))) float f32x4;

// bf16 split helpers (manual RTN-even; avoids hip_bf16 ctor issues in LDS)
__device__ inline unsigned short f2bf(float v) {
    unsigned int u = __float_as_uint(v);
    unsigned int r = (u + 0x7FFFu + ((u >> 16) & 1u)) >> 16;
    return (unsigned short)r;
}
__device__ inline float bf2f(unsigned short b) {
    return __uint_as_float(((unsigned int)b) << 16);
}

// ============================================================
// Split fp32 weight [n] into 2 or 3 bf16 planes (hi, lo, lo2)
// ============================================================
__global__ void k_split_w(const float* __restrict__ a, unsigned short* __restrict__ p,
                          long planeStride, int n, int levels)
{
    int i = blockIdx.x * 256 + threadIdx.x;
    if (i >= n) return;
    float v = a[i];
    unsigned short h0 = f2bf(v);
    float r1 = v - bf2f(h0);
    unsigned short h1 = f2bf(r1);
    p[i] = h0;
    p[planeStride + i] = h1;
    if (levels == 3) {
        float r2 = r1 - bf2f(h1);
        p[2 * planeStride + i] = f2bf(r2);
    }
}

// ============================================================
// Permute x(B,DF,H,W) -> Bt[n=(b*H+h)][k=(f*W+w)] and split into bf16 planes.
// w stays contiguous on both sides -> coalesced.
// ============================================================
__global__ void k_split_x(const float* __restrict__ x, unsigned short* __restrict__ p,
                          long planeStride, int levels)
{
    int tid = blockIdx.x * 256 + threadIdx.x;  // = n*CIN + k
    if (tid >= BHc * CINc) return;
    int n = tid / CINc, k = tid % CINc;
    int b = n / Hh, h = n % Hh;
    int f = k / Ww, w = k % Ww;
    float v = x[((long)(b * DFc + f) * Hh + h) * Ww + w];
    unsigned short h0 = f2bf(v);
    float r1 = v - bf2f(h0);
    unsigned short h1 = f2bf(r1);
    p[tid] = h0;
    p[planeStride + tid] = h1;
    if (levels == 3) {
        float r2 = r1 - bf2f(h1);
        p[2 * planeStride + tid] = f2bf(r2);
    }
}

// ============================================================
// Split-bf16 MFMA GEMM: C[M x N] fp32 = sum over NP plane-products of
// A_pl[M x K] (bf16, K contig) @ Bt_pl[N x K]^T (bf16, K contig).
// 128x128 tile, BK=32, 256 thr (4 waves, each 64x64 via 4x4 of 16x16x32 MFMA).
// Staging via global_load_lds width=16. Epilogue: C = dot*scale[row]+shift[row].
// Requires M%128==0, N%128==0, K%32==0.
// ============================================================
template<int PL, int NP>
__global__ __launch_bounds__(256) void gemm_mfma(
    const unsigned short* __restrict__ Ag, long strideA,
    const unsigned short* __restrict__ Bg, long strideB,
    float* __restrict__ C, int M, int N, int K,
    const float* __restrict__ scale, const float* __restrict__ shift)
{
    constexpr int PAt[6] = {0, 0, 1, 1, 0, 2};
    constexpr int PBt[6] = {0, 1, 0, 1, 2, 0};
    __shared__ __align__(16) unsigned short As[PL][128 * 32];
    __shared__ __align__(16) unsigned short Bs[PL][128 * 32];
    const int tid = threadIdx.x;
    const int w = tid >> 6;          // wave 0..3
    const int l = tid & 63;
    const int quad = l >> 4, l15 = l & 15;
    const int m0 = blockIdx.y * 128, n0 = blockIdx.x * 128;
    const int rw = (w >> 1) * 64, cw = (w & 1) * 64;

    f32x4 acc[4][4];
#pragma unroll
    for (int i = 0; i < 4; i++)
#pragma unroll
        for (int j = 0; j < 4; j++) acc[i][j] = (f32x4){0.f, 0.f, 0.f, 0.f};

    // staging addressing: wave w stages rows [w*32, w*32+32) of each tile,
    // 2 insts of 16 rows; lane l -> row + (l>>2), byte (l&3)*16 (== base + l*16)
    const int srow = w * 32;
    const int lr = l >> 2;
    const int lc = (l & 3) * 8;  // bf16 elements (16 B)
    const unsigned short* gA[PL];
    const unsigned short* gB[PL];
#pragma unroll
    for (int p = 0; p < PL; p++) {
        gA[p] = Ag + (long)p * strideA + (long)(m0 + srow + lr) * K + lc;
        gB[p] = Bg + (long)p * strideB + (long)(n0 + srow + lr) * K + lc;
    }
    const int ldsOff0 = srow * 32;          // uniform LDS elem offset, half 0
    const int ldsOff1 = (srow + 16) * 32;   // half 1

    for (int k0 = 0; k0 < K; k0 += 32) {
#pragma unroll
        for (int p = 0; p < PL; p++) {
            __builtin_amdgcn_global_load_lds(
                (const __attribute__((address_space(1))) void*)(gA[p] + k0),
                (__attribute__((address_space(3))) void*)&As[p][ldsOff0], 16, 0, 0);
            __builtin_amdgcn_global_load_lds(
                (const __attribute__((address_space(1))) void*)(gA[p] + 16 * K + k0),
                (__attribute__((address_space(3))) void*)&As[p][ldsOff1], 16, 0, 0);
            __builtin_amdgcn_global_load_lds(
                (const __attribute__((address_space(1))) void*)(gB[p] + k0),
                (__attribute__((address_space(3))) void*)&Bs[p][ldsOff0], 16, 0, 0);
            __builtin_amdgcn_global_load_lds(
                (const __attribute__((address_space(1))) void*)(gB[p] + 16 * K + k0),
                (__attribute__((address_space(3))) void*)&Bs[p][ldsOff1], 16, 0, 0);
        }
        __syncthreads();

        short8 af[PL][4], bf[PL][4];
#pragma unroll
        for (int p = 0; p < PL; p++)
#pragma unroll
            for (int i = 0; i < 4; i++) {
                af[p][i] = *(const short8*)&As[p][(rw + i * 16 + l15) * 32 + quad * 8];
                bf[p][i] = *(const short8*)&Bs[p][(cw + i * 16 + l15) * 32 + quad * 8];
            }
#pragma unroll
        for (int t = 0; t < NP; t++) {
            const int pa = PAt[t], pb = PBt[t];
#pragma unroll
            for (int i = 0; i < 4; i++)
#pragma unroll
                for (int j = 0; j < 4; j++)
                    acc[i][j] = __builtin_amdgcn_mfma_f32_16x16x32_bf16(
                        af[pa][i], bf[pb][j], acc[i][j], 0, 0, 0);
        }
        __syncthreads();
    }

    // epilogue: C/D layout col=lane&15, row=quad*4+reg
#pragma unroll
    for (int i = 0; i < 4; i++) {
#pragma unroll
        for (int r = 0; r < 4; r++) {
            int row = m0 + rw + i * 16 + quad * 4 + r;
            float sc = scale[row], sh = shift[row];
#pragma unroll
            for (int j = 0; j < 4; j++) {
                C[(long)row * N + n0 + cw + j * 16 + l15] = acc[i][j][r] * sc + sh;
            }
        }
    }
}

// ============================================================
// NN GEMM (fp32 VALU): C[M x N] = A[M x K] @ B[K x N], both row-major.
// epilogue: C = dot*scale[row] + shift[z*shiftStride + row]  (nullable)
// Used only for the small cls 2nd GEMMs now.
// ============================================================
__global__ __launch_bounds__(256) void gemm_nn(
    const float* __restrict__ A, const float* __restrict__ Bm, float* __restrict__ C,
    int M, int N, int K,
    long batchA, long batchB, long batchC,
    const float* __restrict__ scale, const float* __restrict__ shift, int shiftStride)
{
    __shared__ float As[16][132];
    __shared__ float Bs[16][132];
    const int tid = threadIdx.x;
    const int z = blockIdx.z;
    A += z * batchA; Bm += z * batchB; C += z * batchC;
    const int n0 = blockIdx.x * 128;
    const int m0 = blockIdx.y * 128;
    const int aRow = tid >> 2, aCol = (tid & 3) << 2;
    const int bRow = tid >> 5, bCol = (tid & 31) << 2;
    const int ty = tid >> 4, tx = tid & 15;

    float acc[8][8];
#pragma unroll
    for (int i = 0; i < 8; i++)
#pragma unroll
        for (int j = 0; j < 8; j++) acc[i][j] = 0.f;

    for (int k0 = 0; k0 < K; k0 += 16) {
#pragma unroll
        for (int r = 0; r < 2; r++) {
            int row = m0 + aRow + r * 64;
            float4 av = make_float4(0.f, 0.f, 0.f, 0.f);
            if (row < M) av = *(const float4*)(A + (long)row * K + k0 + aCol);
            As[aCol + 0][aRow + r * 64] = av.x;
            As[aCol + 1][aRow + r * 64] = av.y;
            As[aCol + 2][aRow + r * 64] = av.z;
            As[aCol + 3][aRow + r * 64] = av.w;
        }
#pragma unroll
        for (int r = 0; r < 2; r++) {
            int krow = k0 + bRow + r * 8;
            float4 bv = *(const float4*)(Bm + (long)krow * N + n0 + bCol);
            *(float4*)&Bs[bRow + r * 8][bCol] = bv;
        }
        __syncthreads();
#pragma unroll
        for (int kk = 0; kk < 16; kk++) {
            float4 a0 = *(const float4*)&As[kk][ty * 4];
            float4 a1 = *(const float4*)&As[kk][64 + ty * 4];
            float4 b0 = *(const float4*)&Bs[kk][tx * 4];
            float4 b1 = *(const float4*)&Bs[kk][64 + tx * 4];
            float a[8] = {a0.x, a0.y, a0.z, a0.w, a1.x, a1.y, a1.z, a1.w};
            float b[8] = {b0.x, b0.y, b0.z, b0.w, b1.x, b1.y, b1.z, b1.w};
#pragma unroll
            for (int i = 0; i < 8; i++)
#pragma unroll
                for (int j = 0; j < 8; j++) acc[i][j] += a[i] * b[j];
        }
        __syncthreads();
    }
#pragma unroll
    for (int gi = 0; gi < 2; gi++) {
#pragma unroll
        for (int i = 0; i < 4; i++) {
            int row = m0 + gi * 64 + ty * 4 + i;
            if (row >= M) continue;
            float sc = scale ? scale[row] : 1.f;
            float sh = shift ? shift[(long)z * shiftStride + row] : 0.f;
#pragma unroll
            for (int gj = 0; gj < 2; gj++) {
                float4 o;
                o.x = acc[gi * 4 + i][gj * 4 + 0] * sc + sh;
                o.y = acc[gi * 4 + i][gj * 4 + 1] * sc + sh;
                o.z = acc[gi * 4 + i][gj * 4 + 2] * sc + sh;
                o.w = acc[gi * 4 + i][gj * 4 + 3] * sc + sh;
                *(float4*)(C + (long)row * N + n0 + gj * 64 + tx * 4) = o;
            }
        }
    }
}

// ============================================================
// NT GEMM (fp32): C[M x N] = A[M x K] @ B[N x K]^T, + bias, opt. accumulate.
// 64x64 tile, BK=16, 256 threads, 4x4 microtile. M%64==0,N%64==0,K%16==0.
// ============================================================
__global__ __launch_bounds__(256) void gemm_nt(
    const float* __restrict__ A, const float* __restrict__ Bm, float* __restrict__ C,
    int M, int N, int K, const float* __restrict__ bias, int accumulate)
{
    __shared__ float As[16][68];
    __shared__ float Bs[16][68];
    const int tid = threadIdx.x;
    const int n0 = blockIdx.x * 64;
    const int m0 = blockIdx.y * 64;
    const int lRow = tid >> 2, lCol = (tid & 3) << 2;
    const int ty = tid >> 4, tx = tid & 15;

    float acc[4][4];
#pragma unroll
    for (int i = 0; i < 4; i++)
#pragma unroll
        for (int j = 0; j < 4; j++) acc[i][j] = 0.f;

    for (int k0 = 0; k0 < K; k0 += 16) {
        float4 av = *(const float4*)(A + (long)(m0 + lRow) * K + k0 + lCol);
        As[lCol + 0][lRow] = av.x; As[lCol + 1][lRow] = av.y;
        As[lCol + 2][lRow] = av.z; As[lCol + 3][lRow] = av.w;
        float4 bv = *(const float4*)(Bm + (long)(n0 + lRow) * K + k0 + lCol);
        Bs[lCol + 0][lRow] = bv.x; Bs[lCol + 1][lRow] = bv.y;
        Bs[lCol + 2][lRow] = bv.z; Bs[lCol + 3][lRow] = bv.w;
        __syncthreads();
#pragma unroll
        for (int kk = 0; kk < 16; kk++) {
            float4 a = *(const float4*)&As[kk][ty * 4];
            float4 b = *(const float4*)&Bs[kk][tx * 4];
            float aa[4] = {a.x, a.y, a.z, a.w};
            float bb[4] = {b.x, b.y, b.z, b.w};
#pragma unroll
            for (int i = 0; i < 4; i++)
#pragma unroll
                for (int j = 0; j < 4; j++) acc[i][j] += aa[i] * bb[j];
        }
        __syncthreads();
    }
    const int ncol = n0 + tx * 4;
    float4 bv = make_float4(0.f, 0.f, 0.f, 0.f);
    if (bias) bv = *(const float4*)(bias + ncol);
#pragma unroll
    for (int i = 0; i < 4; i++) {
        int row = m0 + ty * 4 + i;
        float4 o = make_float4(acc[i][0] + bv.x, acc[i][1] + bv.y,
                               acc[i][2] + bv.z, acc[i][3] + bv.w);
        float* cp = C + (long)row * N + ncol;
        if (accumulate) {
            float4 pv = *(const float4*)cp;
            o.x += pv.x; o.y += pv.y; o.z += pv.z; o.w += pv.w;
        }
        *(float4*)cp = o;
    }
}

// scale = g*rsqrt(vr+eps); shift = (b1-mu)*scale + bt
__global__ void k_scale_shift(const float* __restrict__ g, const float* __restrict__ vr,
                              const float* __restrict__ mu, const float* __restrict__ bt,
                              const float* __restrict__ b1,
                              float* __restrict__ scale, float* __restrict__ shift, int n)
{
    int i = blockIdx.x * 256 + threadIdx.x;
    if (i >= n) return;
    float sc = g[i] * rsqrtf(vr[i] + EPSc);
    scale[i] = sc;
    shift[i] = (b1[i] - mu[i]) * sc + bt[i];
}

// ext head: logits (O=2) + softmax + exist reduction. block per (b,nc).
__global__ __launch_bounds__(256) void k_ext_head(
    const float* __restrict__ hbuf, const float* __restrict__ w2, const float* __restrict__ b2,
    float* __restrict__ outExt, int* __restrict__ exist)
{
    __shared__ float red[256];
    const int bc = blockIdx.x;
    const int b = bc / NCc, nc = bc % NCc;
    const int h = threadIdx.x;
    float p0 = 0.f;
    if (h < Hh) {
        const int col = b * Hh + h;
        const float* hp = hbuf + (long)(nc * DSc) * BHc + col;
        const float* w0p = w2 + (nc * 2 + 0) * DSc;
        const float* w1p = w2 + (nc * 2 + 1) * DSc;
        float lg0 = b2[nc * 2 + 0], lg1 = b2[nc * 2 + 1];
        for (int s = 0; s < DSc; s++) {
            float hv = hp[(long)s * BHc];
            lg0 += hv * w0p[s];
            lg1 += hv * w1p[s];
        }
        float mx = fmaxf(lg0, lg1);
        float e0 = expf(lg0 - mx), e1 = expf(lg1 - mx);
        float inv = 1.f / (e0 + e1);
        p0 = e0 * inv;
        float* op = outExt + ((long)bc * Hh + h) * 2;
        op[0] = p0;
        op[1] = e1 * inv;
    }
    red[threadIdx.x] = p0;
    __syncthreads();
    for (int st = 128; st > 0; st >>= 1) {
        if (threadIdx.x < st) red[threadIdx.x] += red[threadIdx.x + st];
        __syncthreads();
    }
    if (threadIdx.x == 0) exist[bc] = (red[0] / Hh > THRc) ? 1 : 0;
}

// cls softmax + argmax: one thread per (nc, col=b*H+h)
__global__ void k_cls_softmax(const float* __restrict__ lg, float* __restrict__ outCls,
                              int* __restrict__ corr)
{
    int tid = blockIdx.x * 256 + threadIdx.x;
    if (tid >= NCc * BHc) return;
    int nc = tid / BHc, col = tid % BHc;
    int b = col / Hh, h = col % Hh;
    const float* p = lg + (long)nc * Ww * BHc + col;
    float mx = -1e30f;
    int bi = 0;
    for (int o = 0; o < Ww; o++) {
        float v = p[(long)o * BHc];
        if (v > mx) { mx = v; bi = o; }
    }
    float sum = 0.f;
    for (int o = 0; o < Ww; o++) sum += expf(p[(long)o * BHc] - mx);
    float inv = 1.f / sum;
    float* op = outCls + ((long)(b * NCc + nc) * Hh + h) * Ww;
    for (int o = 0; o < Ww; o++) op[o] = expf(p[(long)o * BHc] - mx) * inv;
    corr[(b * NCc + nc) * Hh + h] = bi;
}

// gather window: win[(b*NC+nc)][f*H*K + h*K + k]
__global__ void k_gather(const float* __restrict__ x, const int* __restrict__ corr,
                         float* __restrict__ win)
{
    int tid = blockIdx.x * 256 + threadIdx.x;
    if (tid >= Bb * NCc * ITCc) return;
    int row = tid / ITCc, i = tid % ITCc;
    int b = row / NCc, nc = row % NCc;
    int f = i / (Hh * KWc);
    int r = i % (Hh * KWc);
    int h = r / KWc, k = r % KWc;
    int j = corr[(b * NCc + nc) * Hh + h] + k - OFFc;
    float v = 0.f;
    if (j >= 0 && j < Ww) v = x[((long)(b * DFc + f) * Hh + h) * Ww + j];
    win[tid] = v;
}

__global__ void k_add_emb(float* __restrict__ tok, const float* __restrict__ emb)
{
    int tid = blockIdx.x * 256 + threadIdx.x;
    if (tid >= Bb * NCc * DTc) return;
    int row = tid / DTc, n = tid % DTc;
    tok[tid] += emb[(row % NCc) * DTc + n];
}

__global__ __launch_bounds__(256) void k_layernorm(
    const float* __restrict__ in, const float* __restrict__ g,
    const float* __restrict__ bta, float* __restrict__ out)
{
    __shared__ float r1[256], r2[256];
    const int row = blockIdx.x;
    const int t = threadIdx.x;
    const float* p = in + (long)row * DTc;
    float s = 0.f, sq = 0.f;
    for (int i = t; i < DTc; i += 256) {
        float v = p[i];
        s += v; sq += v * v;
    }
    r1[t] = s; r2[t] = sq;
    __syncthreads();
    for (int st = 128; st > 0; st >>= 1) {
        if (t < st) { r1[t] += r1[t + st]; r2[t] += r2[t + st]; }
        __syncthreads();
    }
    float mean = r1[0] / DTc;
    float var = r2[0] / DTc - mean * mean;
    float rstd = rsqrtf(var + EPSc);
    float* o = out + (long)row * DTc;
    for (int i = t; i < DTc; i += 256) o[i] = (p[i] - mean) * rstd * g[i] + bta[i];
}

// tiny attention: one thread per (b, head, n)
__global__ void k_attention(const float* __restrict__ qkv, const int* __restrict__ exist,
                            float* __restrict__ obuf)
{
    int idx = blockIdx.x * 256 + threadIdx.x;
    if (idx >= Bb * HEADSc * NCc) return;
    int b = idx / (HEADSc * NCc);
    int r = idx % (HEADSc * NCc);
    int hd = r / NCc, n = r % NCc;
    const float* base = qkv + (long)b * NCc * (3 * INNERc);
    const float* q = base + (long)n * (3 * INNERc) + hd * DHc;
    float s[NCc];
    for (int m = 0; m < NCc; m++) {
        const float* kp = base + (long)m * (3 * INNERc) + INNERc + hd * DHc;
        float d = 0.f;
        for (int t = 0; t < DHc; t++) d += q[t] * kp[t];
        s[m] = exist[b * NCc + m] ? d * 0.125f : -1e9f;
    }
    float mx = s[0];
    for (int m = 1; m < NCc; m++) mx = fmaxf(mx, s[m]);
    float sum = 0.f;
    for (int m = 0; m < NCc; m++) { s[m] = expf(s[m] - mx); sum += s[m]; }
    float inv = 1.f / sum;
    for (int m = 0; m < NCc; m++) s[m] *= inv;
    float* op = obuf + (long)(b * NCc + n) * INNERc + hd * DHc;
    for (int t = 0; t < DHc; t++) {
        float acc = 0.f;
        for (int m = 0; m < NCc; m++)
            acc += s[m] * base[(long)m * (3 * INNERc) + 2 * INNERc + hd * DHc + t];
        op[t] = acc;
    }
}

__global__ void k_gelu(float* __restrict__ p, int n)
{
    int tid = blockIdx.x * 256 + threadIdx.x;
    if (tid < n) {
        float v = p[tid];
        p[tid] = 0.5f * v * (1.f + erff(v * 0.70710678118654752440f));
    }
}

__global__ void k_copy4(const float4* __restrict__ s, float4* __restrict__ d, int n)
{
    int tid = blockIdx.x * 256 + threadIdx.x;
    if (tid < n) d[tid] = s[tid];
}

// scatter dec into x2; per-(b,h,f) thread, c descending, first-writer-wins per column
// (== reference's sequential c-ascending last-writer-wins).
__global__ void k_scatter(const float* __restrict__ dec, const int* __restrict__ corr,
                          const int* __restrict__ exist, float* __restrict__ x2)
{
    int idx = blockIdx.x * 256 + threadIdx.x;
    if (idx >= Bb * Hh * DFc) return;
    int b = idx / (Hh * DFc);
    int r = idx % (Hh * DFc);
    int h = r / DFc, f = r % DFc;
    if (h >= Hh - 1) return;  // hmask
    unsigned long long m0 = 0ull, m1 = 0ull, m2 = 0ull;
    float* xrow = x2 + ((long)(b * DFc + f) * Hh + h) * Ww;
    for (int c = NCc - 1; c >= 0; c--) {
        if (!exist[b * NCc + c]) continue;
        int cr = corr[(b * NCc + c) * Hh + h];
        const float* dp = dec + (long)(b * NCc + c) * ITCc + f * (Hh * KWc) + h * KWc;
        for (int k = 0; k < KWc; k++) {
            int j = cr + k - OFFc;
            if (j < 0 || j >= Ww) continue;
            bool seen;
            if (j < 64) { unsigned long long bit = 1ull << j; seen = (m0 & bit) != 0; m0 |= bit; }
            else if (j < 128) { unsigned long long bit = 1ull << (j - 64); seen = (m1 & bit) != 0; m1 |= bit; }
            else { unsigned long long bit = 1ull << (j - 128); seen = (m2 & bit) != 0; m2 |= bit; }
            if (!seen) xrow[j] = dp[k];
        }
    }
}

extern "C" void kernel_launch(void* const* d_in, const int* in_sizes, int n_in,
                              void* d_out, int out_size, void* d_ws, size_t ws_size,
                              hipStream_t stream)
{
    const float* const* in = (const float* const*)d_in;
    const float* x = in[0];
    // input index bases: ext=1, cls=9, ext2=17, cls2=25
    // per head: +0 w1, +1 b1, +2 g, +3 bt, +4 mu, +5 vr, +6 w2, +7 b2
    const float* emb = in[33];
    const float* tok_w = in[34]; const float* tok_b = in[35];
    const float* ln1_g = in[36]; const float* ln1_b = in[37];
    const float* qkv_w = in[38];
    const float* out_w = in[39]; const float* out_b = in[40];
    const float* ln2_g = in[41]; const float* ln2_b = in[42];
    const float* ff_w1 = in[43]; const float* ff_b1 = in[44];
    const float* ff_w2 = in[45]; const float* ff_b2 = in[46];
    const float* lnf_g = in[47]; const float* lnf_b = in[48];
    const float* dec_w = in[49]; const float* dec_b = in[50];

    float* out = (float*)d_out;
    float* outExt1 = out;                                  // 32*6*144*2   = 55296
    float* outCls1 = out + 55296;                          // 32*6*144*144 = 3981312
    float* outExt2 = out + 4036608;
    float* outCls2 = out + 4091904;

    // ---- workspace layout (floats), heavy aliasing; total ~110 MB ----
    const long strideA = (long)NCc * DSc * CINc;   // 3,538,944 bf16 per A plane
    const long strideB = (long)BHc * CINc;         // 5,308,416 bf16 per B plane
    float* ws = (float*)d_ws;
    float* hbuf = ws;                                   // 14,155,776 f
    float* x2 = hbuf;                                   // alias: first 5,308,416 f
    unsigned short* Apl = (unsigned short*)(ws + 14155776);  // 3 planes x strideA
    float* clslg = ws + 14155776;                       // alias over Apl (3,981,312 f)
    unsigned short* Bpl = (unsigned short*)(ws + 19464192);  // 3 planes x strideB
    // transformer scratch aliases Bpl region (dead between stage-1 gemms and stage-2 split)
    float* windec = ws + 19464192;                      // 1,105,920
    float* tok  = windec + 1105920;                     // 196,608
    float* ybuf = tok + 196608;                         // 196,608
    float* qkvB = ybuf + 196608;                        // 589,824
    float* obuf = qkvB + 589824;                        // 196,608
    float* ffh  = obuf + 196608;                        // 393,216
    float* scaleB = ws + 27426816;                      // 3072
    float* shiftB = scaleB + 3072;                      // 3072
    int* corrB  = (int*)(shiftB + 3072);                // 27648
    int* existB = corrB + 27648;                        // 192
    float* win = windec;
    float* dec = windec;

    auto run_stage = [&](int be, int bc, float* oExt, float* oCls, bool clsX6) {
        // ext head: bf16x3 MFMA h-GEMM + fused BN epilogue
        k_scale_shift<<<12, 256, 0, stream>>>(in[be + 2], in[be + 5], in[be + 4],
                                              in[be + 3], in[be + 1], scaleB, shiftB, NCc * DSc);
        k_split_w<<<13824, 256, 0, stream>>>(in[be + 0], Apl, strideA, NCc * DSc * CINc, 2);
        gemm_mfma<2, 3><<<dim3(36, 24), 256, 0, stream>>>(Apl, strideA, Bpl, strideB,
                                                          hbuf, NCc * DSc, BHc, CINc,
                                                          scaleB, shiftB);
        k_ext_head<<<Bb * NCc, 256, 0, stream>>>(hbuf, in[be + 6], in[be + 7], oExt, existB);
        // cls head: bf16x6 (argmax-critical, stage 1) or bf16x3 (stage 2)
        k_scale_shift<<<12, 256, 0, stream>>>(in[bc + 2], in[bc + 5], in[bc + 4],
                                              in[bc + 3], in[bc + 1], scaleB, shiftB, NCc * DSc);
        k_split_w<<<13824, 256, 0, stream>>>(in[bc + 0], Apl, strideA, NCc * DSc * CINc,
                                             clsX6 ? 3 : 2);
        if (clsX6)
            gemm_mfma<3, 6><<<dim3(36, 24), 256, 0, stream>>>(Apl, strideA, Bpl, strideB,
                                                              hbuf, NCc * DSc, BHc, CINc,
                                                              scaleB, shiftB);
        else
            gemm_mfma<2, 3><<<dim3(36, 24), 256, 0, stream>>>(Apl, strideA, Bpl, strideB,
                                                              hbuf, NCc * DSc, BHc, CINc,
                                                              scaleB, shiftB);
        // cls 2nd GEMM (fp32, batched over nc) -> clslg (aliases Apl; Apl dead by now)
        gemm_nn<<<dim3(36, 2, NCc), 256, 0, stream>>>(in[bc + 6], hbuf, clslg,
                                                      Ww, BHc, DSc,
                                                      (long)Ww * DSc, (long)DSc * BHc, (long)Ww * BHc,
                                                      nullptr, in[bc + 7], Ww);
        k_cls_softmax<<<108, 256, 0, stream>>>(clslg, oCls, corrB);
    };

    // ======== stage 1 ========
    k_split_x<<<20736, 256, 0, stream>>>(x, Bpl, strideB, 3);
    run_stage(1, 9, outExt1, outCls1, true);

    // gather + token projection (windec etc. alias Bpl region; Bpl stage-1 is dead)
    k_gather<<<4320, 256, 0, stream>>>(x, corrB, win);
    gemm_nt<<<dim3(16, 3), 256, 0, stream>>>(win, tok_w, tok, 192, DTc, ITCc, tok_b, 0);
    k_add_emb<<<768, 256, 0, stream>>>(tok, emb);

    // transformer block
    k_layernorm<<<192, 256, 0, stream>>>(tok, ln1_g, ln1_b, ybuf);
    gemm_nt<<<dim3(48, 3), 256, 0, stream>>>(ybuf, qkv_w, qkvB, 192, 3 * INNERc, DTc, nullptr, 0);
    k_attention<<<12, 256, 0, stream>>>(qkvB, existB, obuf);
    gemm_nt<<<dim3(16, 3), 256, 0, stream>>>(obuf, out_w, tok, 192, DTc, INNERc, out_b, 1);
    k_layernorm<<<192, 256, 0, stream>>>(tok, ln2_g, ln2_b, ybuf);
    gemm_nt<<<dim3(32, 3), 256, 0, stream>>>(ybuf, ff_w1, ffh, 192, MLPc, DTc, ff_b1, 0);
    k_gelu<<<1536, 256, 0, stream>>>(ffh, 192 * MLPc);
    gemm_nt<<<dim3(16, 3), 256, 0, stream>>>(ffh, ff_w2, tok, 192, DTc, MLPc, ff_b2, 1);
    k_layernorm<<<192, 256, 0, stream>>>(tok, lnf_g, lnf_b, ybuf);
    gemm_nt<<<dim3(90, 3), 256, 0, stream>>>(ybuf, dec_w, dec, 192, ITCc, DTc, dec_b, 0);

    // scatter into x2 (copy of x); x2 aliases hbuf (hbuf stage-1 content is dead)
    k_copy4<<<5184, 256, 0, stream>>>((const float4*)x, (float4*)x2, 1327104);
    k_scatter<<<144, 256, 0, stream>>>(dec, corrB, existB, x2);

    // ======== stage 2 ======== (x2 read into Bpl before hbuf is overwritten)
    k_split_x<<<20736, 256, 0, stream>>>(x2, Bpl, strideB, 2);
    run_stage(17, 25, outExt2, outCls2, false);

    (void)in_sizes; (void)n_in; (void)out_size; (void)ws_size;
}

// Round 3
// 1523.294 us; speedup vs baseline: 2.0050x; 1.2284x over previous
//
#include <hip/hip_runtime.h>
#include <math.h>

// ---- problem constants ----
#define Bb 32
#define DFc 8
#define Hh 144
#define Ww 144
#define OFFc 2
#define KWc 5
#define DSc 512
#define DTc 1024
#define NCc 6
#define HEADSc 16
#define DHc 64
#define MLPc 2048
#define CINc (DFc * Ww)        // 1152
#define ITCc (DFc * Hh * KWc)  // 5760
#define BHc (Bb * Hh)          // 4608
#define INNERc (HEADSc * DHc)  // 1024
#define EPSc 1e-5f
#define THRc 0.3f

typedef __attribute__((ext_vector_type(8))) short short8;
typedef __attribute__((ext_vector_type(4))) float f32x4;

#if defined(__gfx90a__) || defined(__gfx940__) || defined(__gfx941__) || \
    defined(__gfx942__) || defined(__gfx950__)
#define ATOMIC_ADD_F32(p, v) unsafeAtomicAdd((p), (v))
#else
#define ATOMIC_ADD_F32(p, v) atomicAdd((p), (v))
#endif

// bf16 split helpers (manual RTN-even)
__device__ inline unsigned short f2bf(float v) {
    unsigned int u = __float_as_uint(v);
    unsigned int r = (u + 0x7FFFu + ((u >> 16) & 1u)) >> 16;
    return (unsigned short)r;
}
__device__ inline float bf2f(unsigned short b) {
    return __uint_as_float(((unsigned int)b) << 16);
}

// ============================================================
// Split fp32 weight [n] into 2 or 3 bf16 planes (hi, lo, lo2)
// ============================================================
__global__ void k_split_w(const float* __restrict__ a, unsigned short* __restrict__ p,
                          long planeStride, int n, int levels)
{
    int i = blockIdx.x * 256 + threadIdx.x;
    if (i >= n) return;
    float v = a[i];
    unsigned short h0 = f2bf(v);
    float r1 = v - bf2f(h0);
    unsigned short h1 = f2bf(r1);
    p[i] = h0;
    p[planeStride + i] = h1;
    if (levels == 3) {
        float r2 = r1 - bf2f(h1);
        p[2 * planeStride + i] = f2bf(r2);
    }
}

// ============================================================
// Permute x(B,DF,H,W) -> Bt[n=(b*H+h)][k=(f*W+w)] and split into bf16 planes.
// ============================================================
__global__ void k_split_x(const float* __restrict__ x, unsigned short* __restrict__ p,
                          long planeStride, int levels)
{
    int tid = blockIdx.x * 256 + threadIdx.x;  // = n*CIN + k
    if (tid >= BHc * CINc) return;
    int n = tid / CINc, k = tid % CINc;
    int b = n / Hh, h = n % Hh;
    int f = k / Ww, w = k % Ww;
    float v = x[((long)(b * DFc + f) * Hh + h) * Ww + w];
    unsigned short h0 = f2bf(v);
    float r1 = v - bf2f(h0);
    unsigned short h1 = f2bf(r1);
    p[tid] = h0;
    p[planeStride + tid] = h1;
    if (levels == 3) {
        float r2 = r1 - bf2f(h1);
        p[2 * planeStride + tid] = f2bf(r2);
    }
}

// ============================================================
// Split-bf16 MFMA GEMM: C[M x N] fp32 = sum over NP plane-products of
// A_pl[M x K] (bf16, K contig) @ Bt_pl[N x K]^T (bf16, K contig).
// 128x128 tile, BK=32, 256 thr (4 waves, each 64x64 via 4x4 of 16x16x32 MFMA).
// Staging via global_load_lds width=16. Epilogue: C = dot*scale[row]+shift[row].
// Requires M%128==0, N%128==0, K%32==0.
// ============================================================
template<int PL, int NP>
__global__ __launch_bounds__(256) void gemm_mfma(
    const unsigned short* __restrict__ Ag, long strideA,
    const unsigned short* __restrict__ Bg, long strideB,
    float* __restrict__ C, int M, int N, int K,
    const float* __restrict__ scale, const float* __restrict__ shift)
{
    constexpr int PAt[6] = {0, 0, 1, 1, 0, 2};
    constexpr int PBt[6] = {0, 1, 0, 1, 2, 0};
    __shared__ __align__(16) unsigned short As[PL][128 * 32];
    __shared__ __align__(16) unsigned short Bs[PL][128 * 32];
    const int tid = threadIdx.x;
    const int w = tid >> 6;          // wave 0..3
    const int l = tid & 63;
    const int quad = l >> 4, l15 = l & 15;
    const int m0 = blockIdx.y * 128, n0 = blockIdx.x * 128;
    const int rw = (w >> 1) * 64, cw = (w & 1) * 64;

    f32x4 acc[4][4];
#pragma unroll
    for (int i = 0; i < 4; i++)
#pragma unroll
        for (int j = 0; j < 4; j++) acc[i][j] = (f32x4){0.f, 0.f, 0.f, 0.f};

    const int srow = w * 32;
    const int lr = l >> 2;
    const int lc = (l & 3) * 8;  // bf16 elements (16 B)
    const unsigned short* gA[PL];
    const unsigned short* gB[PL];
#pragma unroll
    for (int p = 0; p < PL; p++) {
        gA[p] = Ag + (long)p * strideA + (long)(m0 + srow + lr) * K + lc;
        gB[p] = Bg + (long)p * strideB + (long)(n0 + srow + lr) * K + lc;
    }
    const int ldsOff0 = srow * 32;
    const int ldsOff1 = (srow + 16) * 32;

    for (int k0 = 0; k0 < K; k0 += 32) {
#pragma unroll
        for (int p = 0; p < PL; p++) {
            __builtin_amdgcn_global_load_lds(
                (const __attribute__((address_space(1))) void*)(gA[p] + k0),
                (__attribute__((address_space(3))) void*)&As[p][ldsOff0], 16, 0, 0);
            __builtin_amdgcn_global_load_lds(
                (const __attribute__((address_space(1))) void*)(gA[p] + 16 * K + k0),
                (__attribute__((address_space(3))) void*)&As[p][ldsOff1], 16, 0, 0);
            __builtin_amdgcn_global_load_lds(
                (const __attribute__((address_space(1))) void*)(gB[p] + k0),
                (__attribute__((address_space(3))) void*)&Bs[p][ldsOff0], 16, 0, 0);
            __builtin_amdgcn_global_load_lds(
                (const __attribute__((address_space(1))) void*)(gB[p] + 16 * K + k0),
                (__attribute__((address_space(3))) void*)&Bs[p][ldsOff1], 16, 0, 0);
        }
        __syncthreads();

        short8 af[PL][4], bf[PL][4];
#pragma unroll
        for (int p = 0; p < PL; p++)
#pragma unroll
            for (int i = 0; i < 4; i++) {
                af[p][i] = *(const short8*)&As[p][(rw + i * 16 + l15) * 32 + quad * 8];
                bf[p][i] = *(const short8*)&Bs[p][(cw + i * 16 + l15) * 32 + quad * 8];
            }
#pragma unroll
        for (int t = 0; t < NP; t++) {
            const int pa = PAt[t], pb = PBt[t];
#pragma unroll
            for (int i = 0; i < 4; i++)
#pragma unroll
                for (int j = 0; j < 4; j++)
                    acc[i][j] = __builtin_amdgcn_mfma_f32_16x16x32_bf16(
                        af[pa][i], bf[pb][j], acc[i][j], 0, 0, 0);
        }
        __syncthreads();
    }

#pragma unroll
    for (int i = 0; i < 4; i++) {
#pragma unroll
        for (int r = 0; r < 4; r++) {
            int row = m0 + rw + i * 16 + quad * 4 + r;
            float sc = scale[row], sh = shift[row];
#pragma unroll
            for (int j = 0; j < 4; j++) {
                C[(long)row * N + n0 + cw + j * 16 + l15] = acc[i][j][r] * sc + sh;
            }
        }
    }
}

// ============================================================
// NN GEMM (fp32 VALU): C[M x N] = A[M x K] @ B[K x N]. For cls 2nd GEMMs.
// ============================================================
__global__ __launch_bounds__(256) void gemm_nn(
    const float* __restrict__ A, const float* __restrict__ Bm, float* __restrict__ C,
    int M, int N, int K,
    long batchA, long batchB, long batchC,
    const float* __restrict__ scale, const float* __restrict__ shift, int shiftStride)
{
    __shared__ float As[16][132];
    __shared__ float Bs[16][132];
    const int tid = threadIdx.x;
    const int z = blockIdx.z;
    A += z * batchA; Bm += z * batchB; C += z * batchC;
    const int n0 = blockIdx.x * 128;
    const int m0 = blockIdx.y * 128;
    const int aRow = tid >> 2, aCol = (tid & 3) << 2;
    const int bRow = tid >> 5, bCol = (tid & 31) << 2;
    const int ty = tid >> 4, tx = tid & 15;

    float acc[8][8];
#pragma unroll
    for (int i = 0; i < 8; i++)
#pragma unroll
        for (int j = 0; j < 8; j++) acc[i][j] = 0.f;

    for (int k0 = 0; k0 < K; k0 += 16) {
#pragma unroll
        for (int r = 0; r < 2; r++) {
            int row = m0 + aRow + r * 64;
            float4 av = make_float4(0.f, 0.f, 0.f, 0.f);
            if (row < M) av = *(const float4*)(A + (long)row * K + k0 + aCol);
            As[aCol + 0][aRow + r * 64] = av.x;
            As[aCol + 1][aRow + r * 64] = av.y;
            As[aCol + 2][aRow + r * 64] = av.z;
            As[aCol + 3][aRow + r * 64] = av.w;
        }
#pragma unroll
        for (int r = 0; r < 2; r++) {
            int krow = k0 + bRow + r * 8;
            float4 bv = *(const float4*)(Bm + (long)krow * N + n0 + bCol);
            *(float4*)&Bs[bRow + r * 8][bCol] = bv;
        }
        __syncthreads();
#pragma unroll
        for (int kk = 0; kk < 16; kk++) {
            float4 a0 = *(const float4*)&As[kk][ty * 4];
            float4 a1 = *(const float4*)&As[kk][64 + ty * 4];
            float4 b0 = *(const float4*)&Bs[kk][tx * 4];
            float4 b1 = *(const float4*)&Bs[kk][64 + tx * 4];
            float a[8] = {a0.x, a0.y, a0.z, a0.w, a1.x, a1.y, a1.z, a1.w};
            float b[8] = {b0.x, b0.y, b0.z, b0.w, b1.x, b1.y, b1.z, b1.w};
#pragma unroll
            for (int i = 0; i < 8; i++)
#pragma unroll
                for (int j = 0; j < 8; j++) acc[i][j] += a[i] * b[j];
        }
        __syncthreads();
    }
#pragma unroll
    for (int gi = 0; gi < 2; gi++) {
#pragma unroll
        for (int i = 0; i < 4; i++) {
            int row = m0 + gi * 64 + ty * 4 + i;
            if (row >= M) continue;
            float sc = scale ? scale[row] : 1.f;
            float sh = shift ? shift[(long)z * shiftStride + row] : 0.f;
#pragma unroll
            for (int gj = 0; gj < 2; gj++) {
                float4 o;
                o.x = acc[gi * 4 + i][gj * 4 + 0] * sc + sh;
                o.y = acc[gi * 4 + i][gj * 4 + 1] * sc + sh;
                o.z = acc[gi * 4 + i][gj * 4 + 2] * sc + sh;
                o.w = acc[gi * 4 + i][gj * 4 + 3] * sc + sh;
                *(float4*)(C + (long)row * N + n0 + gj * 64 + tx * 4) = o;
            }
        }
    }
}

// ============================================================
// Bias init: mode 0: C[m][n] = bias[n] (or 0); mode 1: C[m][n] += bias[n]
// ============================================================
__global__ void k_bias(float* __restrict__ C, const float* __restrict__ bias,
                       int M, int N, int add)
{
    int idx = blockIdx.x * 256 + threadIdx.x;
    if (idx >= M * N) return;
    int n = idx % N;
    float v = bias ? bias[n] : 0.f;
    C[idx] = add ? C[idx] + v : v;
}

// ============================================================
// Split-K NT GEMM: C[M x N] += A[M x K] @ B[N x K]^T over k-chunk blockIdx.z.
// 64x64 tile, BK=16, 256 threads, 4x4 microtile, fp32 atomic-add epilogue.
// C must be pre-initialized (bias/residual). M%64==0, N%64==0, kc%16==0.
// ============================================================
__global__ __launch_bounds__(256) void gemm_nt_sk(
    const float* __restrict__ A, const float* __restrict__ Bm, float* __restrict__ C,
    int M, int N, int K, int kc)
{
    __shared__ float As[16][68];
    __shared__ float Bs[16][68];
    const int tid = threadIdx.x;
    const int n0 = blockIdx.x * 64;
    const int m0 = blockIdx.y * 64;
    const int ks = blockIdx.z * kc;
    const int ke = min(K, ks + kc);
    const int lRow = tid >> 2, lCol = (tid & 3) << 2;
    const int ty = tid >> 4, tx = tid & 15;

    float acc[4][4];
#pragma unroll
    for (int i = 0; i < 4; i++)
#pragma unroll
        for (int j = 0; j < 4; j++) acc[i][j] = 0.f;

    for (int k0 = ks; k0 < ke; k0 += 16) {
        float4 av = *(const float4*)(A + (long)(m0 + lRow) * K + k0 + lCol);
        As[lCol + 0][lRow] = av.x; As[lCol + 1][lRow] = av.y;
        As[lCol + 2][lRow] = av.z; As[lCol + 3][lRow] = av.w;
        float4 bv = *(const float4*)(Bm + (long)(n0 + lRow) * K + k0 + lCol);
        Bs[lCol + 0][lRow] = bv.x; Bs[lCol + 1][lRow] = bv.y;
        Bs[lCol + 2][lRow] = bv.z; Bs[lCol + 3][lRow] = bv.w;
        __syncthreads();
#pragma unroll
        for (int kk = 0; kk < 16; kk++) {
            float4 a = *(const float4*)&As[kk][ty * 4];
            float4 b = *(const float4*)&Bs[kk][tx * 4];
            float aa[4] = {a.x, a.y, a.z, a.w};
            float bb[4] = {b.x, b.y, b.z, b.w};
#pragma unroll
            for (int i = 0; i < 4; i++)
#pragma unroll
                for (int j = 0; j < 4; j++) acc[i][j] += aa[i] * bb[j];
        }
        __syncthreads();
    }
    const int ncol = n0 + tx * 4;
#pragma unroll
    for (int i = 0; i < 4; i++) {
        int row = m0 + ty * 4 + i;
        float* cp = C + (long)row * N + ncol;
#pragma unroll
        for (int j = 0; j < 4; j++) ATOMIC_ADD_F32(cp + j, acc[i][j]);
    }
}

// scale = g*rsqrt(vr+eps); shift = (b1-mu)*scale + bt
__global__ void k_scale_shift(const float* __restrict__ g, const float* __restrict__ vr,
                              const float* __restrict__ mu, const float* __restrict__ bt,
                              const float* __restrict__ b1,
                              float* __restrict__ scale, float* __restrict__ shift, int n)
{
    int i = blockIdx.x * 256 + threadIdx.x;
    if (i >= n) return;
    float sc = g[i] * rsqrtf(vr[i] + EPSc);
    scale[i] = sc;
    shift[i] = (b1[i] - mu[i]) * sc + bt[i];
}

// ext head: logits (O=2) + softmax + exist reduction. block per (b,nc).
__global__ __launch_bounds__(256) void k_ext_head(
    const float* __restrict__ hbuf, const float* __restrict__ w2, const float* __restrict__ b2,
    float* __restrict__ outExt, int* __restrict__ exist)
{
    __shared__ float red[256];
    const int bc = blockIdx.x;
    const int b = bc / NCc, nc = bc % NCc;
    const int h = threadIdx.x;
    float p0 = 0.f;
    if (h < Hh) {
        const int col = b * Hh + h;
        const float* hp = hbuf + (long)(nc * DSc) * BHc + col;
        const float* w0p = w2 + (nc * 2 + 0) * DSc;
        const float* w1p = w2 + (nc * 2 + 1) * DSc;
        float lg0 = b2[nc * 2 + 0], lg1 = b2[nc * 2 + 1];
        for (int s = 0; s < DSc; s++) {
            float hv = hp[(long)s * BHc];
            lg0 += hv * w0p[s];
            lg1 += hv * w1p[s];
        }
        float mx = fmaxf(lg0, lg1);
        float e0 = expf(lg0 - mx), e1 = expf(lg1 - mx);
        float inv = 1.f / (e0 + e1);
        p0 = e0 * inv;
        float* op = outExt + ((long)bc * Hh + h) * 2;
        op[0] = p0;
        op[1] = e1 * inv;
    }
    red[threadIdx.x] = p0;
    __syncthreads();
    for (int st = 128; st > 0; st >>= 1) {
        if (threadIdx.x < st) red[threadIdx.x] += red[threadIdx.x + st];
        __syncthreads();
    }
    if (threadIdx.x == 0) exist[bc] = (red[0] / Hh > THRc) ? 1 : 0;
}

// cls softmax + argmax: one thread per (nc, col=b*H+h)
__global__ void k_cls_softmax(const float* __restrict__ lg, float* __restrict__ outCls,
                              int* __restrict__ corr)
{
    int tid = blockIdx.x * 256 + threadIdx.x;
    if (tid >= NCc * BHc) return;
    int nc = tid / BHc, col = tid % BHc;
    int b = col / Hh, h = col % Hh;
    const float* p = lg + (long)nc * Ww * BHc + col;
    float mx = -1e30f;
    int bi = 0;
    for (int o = 0; o < Ww; o++) {
        float v = p[(long)o * BHc];
        if (v > mx) { mx = v; bi = o; }
    }
    float sum = 0.f;
    for (int o = 0; o < Ww; o++) sum += expf(p[(long)o * BHc] - mx);
    float inv = 1.f / sum;
    float* op = outCls + ((long)(b * NCc + nc) * Hh + h) * Ww;
    for (int o = 0; o < Ww; o++) op[o] = expf(p[(long)o * BHc] - mx) * inv;
    corr[(b * NCc + nc) * Hh + h] = bi;
}

// gather window: win[(b*NC+nc)][f*H*K + h*K + k]
__global__ void k_gather(const float* __restrict__ x, const int* __restrict__ corr,
                         float* __restrict__ win)
{
    int tid = blockIdx.x * 256 + threadIdx.x;
    if (tid >= Bb * NCc * ITCc) return;
    int row = tid / ITCc, i = tid % ITCc;
    int b = row / NCc, nc = row % NCc;
    int f = i / (Hh * KWc);
    int r = i % (Hh * KWc);
    int h = r / KWc, k = r % KWc;
    int j = corr[(b * NCc + nc) * Hh + h] + k - OFFc;
    float v = 0.f;
    if (j >= 0 && j < Ww) v = x[((long)(b * DFc + f) * Hh + h) * Ww + j];
    win[tid] = v;
}

__global__ void k_add_emb(float* __restrict__ tok, const float* __restrict__ emb)
{
    int tid = blockIdx.x * 256 + threadIdx.x;
    if (tid >= Bb * NCc * DTc) return;
    int row = tid / DTc, n = tid % DTc;
    tok[tid] += emb[(row % NCc) * DTc + n];
}

__global__ __launch_bounds__(256) void k_layernorm(
    const float* __restrict__ in, const float* __restrict__ g,
    const float* __restrict__ bta, float* __restrict__ out)
{
    __shared__ float r1[256], r2[256];
    const int row = blockIdx.x;
    const int t = threadIdx.x;
    const float* p = in + (long)row * DTc;
    float s = 0.f, sq = 0.f;
    for (int i = t; i < DTc; i += 256) {
        float v = p[i];
        s += v; sq += v * v;
    }
    r1[t] = s; r2[t] = sq;
    __syncthreads();
    for (int st = 128; st > 0; st >>= 1) {
        if (t < st) { r1[t] += r1[t + st]; r2[t] += r2[t + st]; }
        __syncthreads();
    }
    float mean = r1[0] / DTc;
    float var = r2[0] / DTc - mean * mean;
    float rstd = rsqrtf(var + EPSc);
    float* o = out + (long)row * DTc;
    for (int i = t; i < DTc; i += 256) o[i] = (p[i] - mean) * rstd * g[i] + bta[i];
}

// tiny attention: one thread per (b, head, n)
__global__ void k_attention(const float* __restrict__ qkv, const int* __restrict__ exist,
                            float* __restrict__ obuf)
{
    int idx = blockIdx.x * 256 + threadIdx.x;
    if (idx >= Bb * HEADSc * NCc) return;
    int b = idx / (HEADSc * NCc);
    int r = idx % (HEADSc * NCc);
    int hd = r / NCc, n = r % NCc;
    const float* base = qkv + (long)b * NCc * (3 * INNERc);
    const float* q = base + (long)n * (3 * INNERc) + hd * DHc;
    float s[NCc];
    for (int m = 0; m < NCc; m++) {
        const float* kp = base + (long)m * (3 * INNERc) + INNERc + hd * DHc;
        float d = 0.f;
        for (int t = 0; t < DHc; t++) d += q[t] * kp[t];
        s[m] = exist[b * NCc + m] ? d * 0.125f : -1e9f;
    }
    float mx = s[0];
    for (int m = 1; m < NCc; m++) mx = fmaxf(mx, s[m]);
    float sum = 0.f;
    for (int m = 0; m < NCc; m++) { s[m] = expf(s[m] - mx); sum += s[m]; }
    float inv = 1.f / sum;
    for (int m = 0; m < NCc; m++) s[m] *= inv;
    float* op = obuf + (long)(b * NCc + n) * INNERc + hd * DHc;
    for (int t = 0; t < DHc; t++) {
        float acc = 0.f;
        for (int m = 0; m < NCc; m++)
            acc += s[m] * base[(long)m * (3 * INNERc) + 2 * INNERc + hd * DHc + t];
        op[t] = acc;
    }
}

__global__ void k_gelu(float* __restrict__ p, int n)
{
    int tid = blockIdx.x * 256 + threadIdx.x;
    if (tid < n) {
        float v = p[tid];
        p[tid] = 0.5f * v * (1.f + erff(v * 0.70710678118654752440f));
    }
}

__global__ void k_copy4(const float4* __restrict__ s, float4* __restrict__ d, int n)
{
    int tid = blockIdx.x * 256 + threadIdx.x;
    if (tid < n) d[tid] = s[tid];
}

// scatter dec into x2; per-(b,h,f) thread, c descending, first-writer-wins per column
__global__ void k_scatter(const float* __restrict__ dec, const int* __restrict__ corr,
                          const int* __restrict__ exist, float* __restrict__ x2)
{
    int idx = blockIdx.x * 256 + threadIdx.x;
    if (idx >= Bb * Hh * DFc) return;
    int b = idx / (Hh * DFc);
    int r = idx % (Hh * DFc);
    int h = r / DFc, f = r % DFc;
    if (h >= Hh - 1) return;  // hmask
    unsigned long long m0 = 0ull, m1 = 0ull, m2 = 0ull;
    float* xrow = x2 + ((long)(b * DFc + f) * Hh + h) * Ww;
    for (int c = NCc - 1; c >= 0; c--) {
        if (!exist[b * NCc + c]) continue;
        int cr = corr[(b * NCc + c) * Hh + h];
        const float* dp = dec + (long)(b * NCc + c) * ITCc + f * (Hh * KWc) + h * KWc;
        for (int k = 0; k < KWc; k++) {
            int j = cr + k - OFFc;
            if (j < 0 || j >= Ww) continue;
            bool seen;
            if (j < 64) { unsigned long long bit = 1ull << j; seen = (m0 & bit) != 0; m0 |= bit; }
            else if (j < 128) { unsigned long long bit = 1ull << (j - 64); seen = (m1 & bit) != 0; m1 |= bit; }
            else { unsigned long long bit = 1ull << (j - 128); seen = (m2 & bit) != 0; m2 |= bit; }
            if (!seen) xrow[j] = dp[k];
        }
    }
}

extern "C" void kernel_launch(void* const* d_in, const int* in_sizes, int n_in,
                              void* d_out, int out_size, void* d_ws, size_t ws_size,
                              hipStream_t stream)
{
    const float* const* in = (const float* const*)d_in;
    const float* x = in[0];
    // input index bases: ext=1, cls=9, ext2=17, cls2=25
    const float* emb = in[33];
    const float* tok_w = in[34]; const float* tok_b = in[35];
    const float* ln1_g = in[36]; const float* ln1_b = in[37];
    const float* qkv_w = in[38];
    const float* out_w = in[39]; const float* out_b = in[40];
    const float* ln2_g = in[41]; const float* ln2_b = in[42];
    const float* ff_w1 = in[43]; const float* ff_b1 = in[44];
    const float* ff_w2 = in[45]; const float* ff_b2 = in[46];
    const float* lnf_g = in[47]; const float* lnf_b = in[48];
    const float* dec_w = in[49]; const float* dec_b = in[50];

    float* out = (float*)d_out;
    float* outExt1 = out;                                  // 32*6*144*2   = 55296
    float* outCls1 = out + 55296;                          // 32*6*144*144 = 3981312
    float* outExt2 = out + 4036608;
    float* outCls2 = out + 4091904;

    // ---- workspace layout (floats), heavy aliasing ----
    const long strideA = (long)NCc * DSc * CINc;   // 3,538,944 bf16 per A plane
    const long strideB = (long)BHc * CINc;         // 5,308,416 bf16 per B plane
    float* ws = (float*)d_ws;
    float* hbuf = ws;                                   // 14,155,776 f
    float* x2 = hbuf;                                   // alias: first 5,308,416 f
    unsigned short* Apl = (unsigned short*)(ws + 14155776);  // 3 planes x strideA
    float* clslg = ws + 14155776;                       // alias over Apl
    unsigned short* Bpl = (unsigned short*)(ws + 19464192);  // 3 planes x strideB
    float* windec = ws + 19464192;                      // 1,105,920 (aliases Bpl)
    float* tok  = windec + 1105920;                     // 196,608
    float* ybuf = tok + 196608;                         // 196,608
    float* qkvB = ybuf + 196608;                        // 589,824
    float* obuf = qkvB + 589824;                        // 196,608
    float* ffh  = obuf + 196608;                        // 393,216
    float* scaleB = ws + 27426816;                      // 3072
    float* shiftB = scaleB + 3072;                      // 3072
    int* corrB  = (int*)(shiftB + 3072);                // 27648
    int* existB = corrB + 27648;                        // 192
    float* win = windec;
    float* dec = windec;

    auto run_stage = [&](int be, int bc, float* oExt, float* oCls, bool clsX6) {
        k_scale_shift<<<12, 256, 0, stream>>>(in[be + 2], in[be + 5], in[be + 4],
                                              in[be + 3], in[be + 1], scaleB, shiftB, NCc * DSc);
        k_split_w<<<13824, 256, 0, stream>>>(in[be + 0], Apl, strideA, NCc * DSc * CINc, 2);
        gemm_mfma<2, 3><<<dim3(36, 24), 256, 0, stream>>>(Apl, strideA, Bpl, strideB,
                                                          hbuf, NCc * DSc, BHc, CINc,
                                                          scaleB, shiftB);
        k_ext_head<<<Bb * NCc, 256, 0, stream>>>(hbuf, in[be + 6], in[be + 7], oExt, existB);
        k_scale_shift<<<12, 256, 0, stream>>>(in[bc + 2], in[bc + 5], in[bc + 4],
                                              in[bc + 3], in[bc + 1], scaleB, shiftB, NCc * DSc);
        k_split_w<<<13824, 256, 0, stream>>>(in[bc + 0], Apl, strideA, NCc * DSc * CINc,
                                             clsX6 ? 3 : 2);
        if (clsX6)
            gemm_mfma<3, 6><<<dim3(36, 24), 256, 0, stream>>>(Apl, strideA, Bpl, strideB,
                                                              hbuf, NCc * DSc, BHc, CINc,
                                                              scaleB, shiftB);
        else
            gemm_mfma<2, 3><<<dim3(36, 24), 256, 0, stream>>>(Apl, strideA, Bpl, strideB,
                                                              hbuf, NCc * DSc, BHc, CINc,
                                                              scaleB, shiftB);
        gemm_nn<<<dim3(36, 2, NCc), 256, 0, stream>>>(in[bc + 6], hbuf, clslg,
                                                      Ww, BHc, DSc,
                                                      (long)Ww * DSc, (long)DSc * BHc, (long)Ww * BHc,
                                                      nullptr, in[bc + 7], Ww);
        k_cls_softmax<<<108, 256, 0, stream>>>(clslg, oCls, corrB);
    };

    // ======== stage 1 ========
    k_split_x<<<20736, 256, 0, stream>>>(x, Bpl, strideB, 3);
    run_stage(1, 9, outExt1, outCls1, true);

    // gather + token projection (split-K; C pre-init with bias)
    k_gather<<<4320, 256, 0, stream>>>(x, corrB, win);
    k_bias<<<768, 256, 0, stream>>>(tok, tok_b, 192, DTc, 0);
    gemm_nt_sk<<<dim3(16, 3, 8), 256, 0, stream>>>(win, tok_w, tok, 192, DTc, ITCc, 720);
    k_add_emb<<<768, 256, 0, stream>>>(tok, emb);

    // transformer block (all skinny GEMMs split-K + atomic accumulate)
    k_layernorm<<<192, 256, 0, stream>>>(tok, ln1_g, ln1_b, ybuf);
    k_bias<<<2304, 256, 0, stream>>>(qkvB, nullptr, 192, 3 * INNERc, 0);
    gemm_nt_sk<<<dim3(48, 3, 4), 256, 0, stream>>>(ybuf, qkv_w, qkvB, 192, 3 * INNERc, DTc, 256);
    k_attention<<<12, 256, 0, stream>>>(qkvB, existB, obuf);
    k_bias<<<768, 256, 0, stream>>>(tok, out_b, 192, DTc, 1);  // tok += out_b (residual in tok)
    gemm_nt_sk<<<dim3(16, 3, 8), 256, 0, stream>>>(obuf, out_w, tok, 192, DTc, INNERc, 128);
    k_layernorm<<<192, 256, 0, stream>>>(tok, ln2_g, ln2_b, ybuf);
    k_bias<<<1536, 256, 0, stream>>>(ffh, ff_b1, 192, MLPc, 0);
    gemm_nt_sk<<<dim3(32, 3, 4), 256, 0, stream>>>(ybuf, ff_w1, ffh, 192, MLPc, DTc, 256);
    k_gelu<<<1536, 256, 0, stream>>>(ffh, 192 * MLPc);
    k_bias<<<768, 256, 0, stream>>>(tok, ff_b2, 192, DTc, 1);  // tok += ff_b2
    gemm_nt_sk<<<dim3(16, 3, 8), 256, 0, stream>>>(ffh, ff_w2, tok, 192, DTc, MLPc, 256);
    k_layernorm<<<192, 256, 0, stream>>>(tok, lnf_g, lnf_b, ybuf);
    k_bias<<<4320, 256, 0, stream>>>(dec, dec_b, 192, ITCc, 0);
    gemm_nt_sk<<<dim3(90, 3, 2), 256, 0, stream>>>(ybuf, dec_w, dec, 192, ITCc, DTc, 512);

    // scatter into x2 (copy of x); x2 aliases hbuf
    k_copy4<<<5184, 256, 0, stream>>>((const float4*)x, (float4*)x2, 1327104);
    k_scatter<<<144, 256, 0, stream>>>(dec, corrB, existB, x2);

    // ======== stage 2 ========
    k_split_x<<<20736, 256, 0, stream>>>(x2, Bpl, strideB, 2);
    run_stage(17, 25, outExt2, outCls2, false);

    (void)in_sizes; (void)n_in; (void)out_size; (void)ws_size;
}

// Round 4
// 1494.796 us; speedup vs baseline: 2.0433x; 1.0191x over previous
//
#include <hip/hip_runtime.h>
#include <math.h>

// ---- problem constants ----
#define Bb 32
#define DFc 8
#define Hh 144
#define Ww 144
#define OFFc 2
#define KWc 5
#define DSc 512
#define DTc 1024
#define NCc 6
#define HEADSc 16
#define DHc 64
#define MLPc 2048
#define CINc (DFc * Ww)        // 1152
#define ITCc (DFc * Hh * KWc)  // 5760
#define BHc (Bb * Hh)          // 4608
#define INNERc (HEADSc * DHc)  // 1024
#define EPSc 1e-5f
#define THRc 0.3f
#define WLCAP 8192
#define GAPDELTA 1e-3f

typedef __attribute__((ext_vector_type(8))) short short8;
typedef __attribute__((ext_vector_type(4))) float f32x4;

#define ATOMIC_ADD_F32(p, v) unsafeAtomicAdd((p), (v))

// bf16 split helpers (manual RTN-even)
__device__ inline unsigned short f2bf(float v) {
    unsigned int u = __float_as_uint(v);
    unsigned int r = (u + 0x7FFFu + ((u >> 16) & 1u)) >> 16;
    return (unsigned short)r;
}
__device__ inline float bf2f(unsigned short b) {
    return __uint_as_float(((unsigned int)b) << 16);
}

// ============================================================
// Split fp32 weight [n] into 2 bf16 planes (hi, lo)
// ============================================================
__global__ void k_split_w(const float* __restrict__ a, unsigned short* __restrict__ p,
                          long planeStride, int n)
{
    int i = blockIdx.x * 256 + threadIdx.x;
    if (i >= n) return;
    float v = a[i];
    unsigned short h0 = f2bf(v);
    float r1 = v - bf2f(h0);
    p[i] = h0;
    p[planeStride + i] = f2bf(r1);
}

// ============================================================
// Split cls_w2 (NC,144,512) into padded planes [nc][256][512] (zero pad rows)
// ============================================================
__global__ void k_split_w2(const float* __restrict__ w2, unsigned short* __restrict__ p,
                           long planeStride)
{
    int i = blockIdx.x * 256 + threadIdx.x;  // over 6*256*512
    if (i >= NCc * 256 * 512) return;
    int s = i & 511;
    int o = (i >> 9) & 255;
    int nc = i >> 17;
    unsigned short h0 = 0, h1 = 0;
    if (o < 144) {
        float v = w2[((long)(nc * 144 + o)) * 512 + s];
        h0 = f2bf(v);
        h1 = f2bf(v - bf2f(h0));
    }
    p[i] = h0;
    p[planeStride + i] = h1;
}

// ============================================================
// Permute x(B,DF,H,W) -> Bt[n=(b*H+h)][k=(f*W+w)] and split into 2 bf16 planes.
// ============================================================
__global__ void k_split_x(const float* __restrict__ x, unsigned short* __restrict__ p,
                          long planeStride)
{
    int tid = blockIdx.x * 256 + threadIdx.x;  // = n*CIN + k
    if (tid >= BHc * CINc) return;
    int n = tid / CINc, k = tid % CINc;
    int b = n / Hh, h = n % Hh;
    int f = k / Ww, w = k % Ww;
    float v = x[((long)(b * DFc + f) * Hh + h) * Ww + w];
    unsigned short h0 = f2bf(v);
    p[tid] = h0;
    p[planeStride + tid] = f2bf(v - bf2f(h0));
}

// ============================================================
// Split-bf16 MFMA GEMM: C = sum over NP plane-products of A_pl @ B_pl^T.
// 128x128 tile, BK=32, 256 thr (4 waves, each 64x64 via 4x4 of 16x16x32 MFMA).
// MODE 0: fp32 C[row][col] = dot*scale[row]+shift[row]
// MODE 1: bf16 2-plane transposed store hp[nc][col][s] (s=row&511, nc=row>>9),
//         value = dot*scale[row]+shift[row], packed 4-s-wide ushort4 stores.
// ============================================================
template<int PL, int NP, int MODE>
__global__ __launch_bounds__(256) void gemm_mfma(
    const unsigned short* __restrict__ Ag, long strideA,
    const unsigned short* __restrict__ Bg, long strideB,
    void* __restrict__ Cv, int M, int N, int K,
    const float* __restrict__ scale, const float* __restrict__ shift)
{
    constexpr int PAt[3] = {0, 0, 1};
    constexpr int PBt[3] = {0, 1, 0};
    __shared__ __align__(16) unsigned short As[PL][128 * 32];
    __shared__ __align__(16) unsigned short Bs[PL][128 * 32];
    const int tid = threadIdx.x;
    const int w = tid >> 6;
    const int l = tid & 63;
    const int quad = l >> 4, l15 = l & 15;
    const int m0 = blockIdx.y * 128, n0 = blockIdx.x * 128;
    const int rw = (w >> 1) * 64, cw = (w & 1) * 64;

    f32x4 acc[4][4];
#pragma unroll
    for (int i = 0; i < 4; i++)
#pragma unroll
        for (int j = 0; j < 4; j++) acc[i][j] = (f32x4){0.f, 0.f, 0.f, 0.f};

    const int srow = w * 32;
    const int lr = l >> 2;
    const int lc = (l & 3) * 8;
    const unsigned short* gA[PL];
    const unsigned short* gB[PL];
#pragma unroll
    for (int p = 0; p < PL; p++) {
        gA[p] = Ag + (long)p * strideA + (long)(m0 + srow + lr) * K + lc;
        gB[p] = Bg + (long)p * strideB + (long)(n0 + srow + lr) * K + lc;
    }
    const int ldsOff0 = srow * 32;
    const int ldsOff1 = (srow + 16) * 32;

    for (int k0 = 0; k0 < K; k0 += 32) {
#pragma unroll
        for (int p = 0; p < PL; p++) {
            __builtin_amdgcn_global_load_lds(
                (const __attribute__((address_space(1))) void*)(gA[p] + k0),
                (__attribute__((address_space(3))) void*)&As[p][ldsOff0], 16, 0, 0);
            __builtin_amdgcn_global_load_lds(
                (const __attribute__((address_space(1))) void*)(gA[p] + 16 * K + k0),
                (__attribute__((address_space(3))) void*)&As[p][ldsOff1], 16, 0, 0);
            __builtin_amdgcn_global_load_lds(
                (const __attribute__((address_space(1))) void*)(gB[p] + k0),
                (__attribute__((address_space(3))) void*)&Bs[p][ldsOff0], 16, 0, 0);
            __builtin_amdgcn_global_load_lds(
                (const __attribute__((address_space(1))) void*)(gB[p] + 16 * K + k0),
                (__attribute__((address_space(3))) void*)&Bs[p][ldsOff1], 16, 0, 0);
        }
        __syncthreads();

        short8 af[PL][4], bf[PL][4];
#pragma unroll
        for (int p = 0; p < PL; p++)
#pragma unroll
            for (int i = 0; i < 4; i++) {
                af[p][i] = *(const short8*)&As[p][(rw + i * 16 + l15) * 32 + quad * 8];
                bf[p][i] = *(const short8*)&Bs[p][(cw + i * 16 + l15) * 32 + quad * 8];
            }
#pragma unroll
        for (int t = 0; t < NP; t++) {
            const int pa = PAt[t], pb = PBt[t];
#pragma unroll
            for (int i = 0; i < 4; i++)
#pragma unroll
                for (int j = 0; j < 4; j++)
                    acc[i][j] = __builtin_amdgcn_mfma_f32_16x16x32_bf16(
                        af[pa][i], bf[pb][j], acc[i][j], 0, 0, 0);
        }
        __syncthreads();
    }

    if (MODE == 0) {
        float* C = (float*)Cv;
#pragma unroll
        for (int i = 0; i < 4; i++) {
#pragma unroll
            for (int r = 0; r < 4; r++) {
                int row = m0 + rw + i * 16 + quad * 4 + r;
                float sc = scale[row], sh = shift[row];
#pragma unroll
                for (int j = 0; j < 4; j++)
                    C[(long)row * N + n0 + cw + j * 16 + l15] = acc[i][j][r] * sc + sh;
            }
        }
    } else {
        unsigned short* hp = (unsigned short*)Cv;
        const long planeH = (long)NCc * BHc * DSc;
#pragma unroll
        for (int i = 0; i < 4; i++) {
            int row0 = m0 + rw + i * 16 + quad * 4;
            float4 sc4 = *(const float4*)(scale + row0);
            float4 sh4 = *(const float4*)(shift + row0);
            int nc = row0 >> 9, s0 = row0 & 511;
#pragma unroll
            for (int j = 0; j < 4; j++) {
                int col = n0 + cw + j * 16 + l15;
                float v0 = acc[i][j][0] * sc4.x + sh4.x;
                float v1 = acc[i][j][1] * sc4.y + sh4.y;
                float v2 = acc[i][j][2] * sc4.z + sh4.z;
                float v3 = acc[i][j][3] * sc4.w + sh4.w;
                ushort4 hi, lo;
                hi.x = f2bf(v0); lo.x = f2bf(v0 - bf2f(hi.x));
                hi.y = f2bf(v1); lo.y = f2bf(v1 - bf2f(hi.y));
                hi.z = f2bf(v2); lo.z = f2bf(v2 - bf2f(hi.z));
                hi.w = f2bf(v3); lo.w = f2bf(v3 - bf2f(hi.w));
                long off = ((long)nc * BHc + col) * 512 + s0;
                *(ushort4*)(hp + off) = hi;
                *(ushort4*)(hp + planeH + off) = lo;
            }
        }
    }
}

// ============================================================
// cls 2nd GEMM (MFMA): lgT[nc][col][o] = W2[nc] @ h[nc] + b2, transposed store.
// A = padded w2 planes [nc][256][512], B = h planes [nc][4608][512].
// Grid (36, 2, 6), tiles 128x128, BK=32, 2 planes, 3 products.
// ============================================================
__global__ __launch_bounds__(256) void gemm_cls2(
    const unsigned short* __restrict__ Ag, long strideA,
    const unsigned short* __restrict__ Bg, long strideB,
    float* __restrict__ lgT, const float* __restrict__ b2)
{
    constexpr int PAt[3] = {0, 0, 1};
    constexpr int PBt[3] = {0, 1, 0};
    __shared__ __align__(16) unsigned short As[2][128 * 32];
    __shared__ __align__(16) unsigned short Bs[2][128 * 32];
    const int tid = threadIdx.x;
    const int w = tid >> 6;
    const int l = tid & 63;
    const int quad = l >> 4, l15 = l & 15;
    const int z = blockIdx.z;
    const int m0 = blockIdx.y * 128, n0 = blockIdx.x * 128;
    const int rw = (w >> 1) * 64, cw = (w & 1) * 64;

    f32x4 acc[4][4];
#pragma unroll
    for (int i = 0; i < 4; i++)
#pragma unroll
        for (int j = 0; j < 4; j++) acc[i][j] = (f32x4){0.f, 0.f, 0.f, 0.f};

    const int srow = w * 32;
    const int lr = l >> 2;
    const int lc = (l & 3) * 8;
    const unsigned short* gA[2];
    const unsigned short* gB[2];
#pragma unroll
    for (int p = 0; p < 2; p++) {
        gA[p] = Ag + (long)p * strideA + ((long)(z * 256 + m0 + srow + lr)) * 512 + lc;
        gB[p] = Bg + (long)p * strideB + ((long)(z * BHc + n0 + srow + lr)) * 512 + lc;
    }
    const int ldsOff0 = srow * 32;
    const int ldsOff1 = (srow + 16) * 32;

    for (int k0 = 0; k0 < 512; k0 += 32) {
#pragma unroll
        for (int p = 0; p < 2; p++) {
            __builtin_amdgcn_global_load_lds(
                (const __attribute__((address_space(1))) void*)(gA[p] + k0),
                (__attribute__((address_space(3))) void*)&As[p][ldsOff0], 16, 0, 0);
            __builtin_amdgcn_global_load_lds(
                (const __attribute__((address_space(1))) void*)(gA[p] + 16 * 512 + k0),
                (__attribute__((address_space(3))) void*)&As[p][ldsOff1], 16, 0, 0);
            __builtin_amdgcn_global_load_lds(
                (const __attribute__((address_space(1))) void*)(gB[p] + k0),
                (__attribute__((address_space(3))) void*)&Bs[p][ldsOff0], 16, 0, 0);
            __builtin_amdgcn_global_load_lds(
                (const __attribute__((address_space(1))) void*)(gB[p] + 16 * 512 + k0),
                (__attribute__((address_space(3))) void*)&Bs[p][ldsOff1], 16, 0, 0);
        }
        __syncthreads();

        short8 af[2][4], bf[2][4];
#pragma unroll
        for (int p = 0; p < 2; p++)
#pragma unroll
            for (int i = 0; i < 4; i++) {
                af[p][i] = *(const short8*)&As[p][(rw + i * 16 + l15) * 32 + quad * 8];
                bf[p][i] = *(const short8*)&Bs[p][(cw + i * 16 + l15) * 32 + quad * 8];
            }
#pragma unroll
        for (int t = 0; t < 3; t++) {
            const int pa = PAt[t], pb = PBt[t];
#pragma unroll
            for (int i = 0; i < 4; i++)
#pragma unroll
                for (int j = 0; j < 4; j++)
                    acc[i][j] = __builtin_amdgcn_mfma_f32_16x16x32_bf16(
                        af[pa][i], bf[pb][j], acc[i][j], 0, 0, 0);
        }
        __syncthreads();
    }

#pragma unroll
    for (int i = 0; i < 4; i++) {
        int ob = m0 + rw + i * 16 + quad * 4;
        if (ob >= 144) continue;
        float4 bb = *(const float4*)(b2 + z * 144 + ob);
#pragma unroll
        for (int j = 0; j < 4; j++) {
            int col = n0 + cw + j * 16 + l15;
            float4 v = make_float4(acc[i][j][0] + bb.x, acc[i][j][1] + bb.y,
                                   acc[i][j][2] + bb.z, acc[i][j][3] + bb.w);
            *(float4*)(lgT + ((long)(z * BHc + col)) * 144 + ob) = v;
        }
    }
}

// ============================================================
// Bias init: mode 0: C[m][n] = bias[n] (or 0); mode 1: C[m][n] += bias[n]
// ============================================================
__global__ void k_bias(float* __restrict__ C, const float* __restrict__ bias,
                       int M, int N, int add)
{
    int idx = blockIdx.x * 256 + threadIdx.x;
    if (idx >= M * N) return;
    int n = idx % N;
    float v = bias ? bias[n] : 0.f;
    C[idx] = add ? C[idx] + v : v;
}

// tok init: tok[row][n] = tok_b[n] + emb[row%NC][n]
__global__ void k_tok_init(float* __restrict__ tok, const float* __restrict__ tok_b,
                           const float* __restrict__ emb)
{
    int tid = blockIdx.x * 256 + threadIdx.x;
    if (tid >= Bb * NCc * DTc) return;
    int row = tid >> 10, n = tid & 1023;
    tok[tid] = tok_b[n] + emb[(row % NCc) * DTc + n];
}

// ============================================================
// Split-K NT GEMM: C += A[MxK] @ B[NxK]^T over k-chunk blockIdx.z.
// 64x64 tile, BK=16, 4x4 microtile, fp32 atomic-add epilogue. C pre-initialized.
// ============================================================
__global__ __launch_bounds__(256) void gemm_nt_sk(
    const float* __restrict__ A, const float* __restrict__ Bm, float* __restrict__ C,
    int M, int N, int K, int kc)
{
    __shared__ float As[16][68];
    __shared__ float Bs[16][68];
    const int tid = threadIdx.x;
    const int n0 = blockIdx.x * 64;
    const int m0 = blockIdx.y * 64;
    const int ks = blockIdx.z * kc;
    const int ke = min(K, ks + kc);
    const int lRow = tid >> 2, lCol = (tid & 3) << 2;
    const int ty = tid >> 4, tx = tid & 15;

    float acc[4][4];
#pragma unroll
    for (int i = 0; i < 4; i++)
#pragma unroll
        for (int j = 0; j < 4; j++) acc[i][j] = 0.f;

    for (int k0 = ks; k0 < ke; k0 += 16) {
        float4 av = *(const float4*)(A + (long)(m0 + lRow) * K + k0 + lCol);
        As[lCol + 0][lRow] = av.x; As[lCol + 1][lRow] = av.y;
        As[lCol + 2][lRow] = av.z; As[lCol + 3][lRow] = av.w;
        float4 bv = *(const float4*)(Bm + (long)(n0 + lRow) * K + k0 + lCol);
        Bs[lCol + 0][lRow] = bv.x; Bs[lCol + 1][lRow] = bv.y;
        Bs[lCol + 2][lRow] = bv.z; Bs[lCol + 3][lRow] = bv.w;
        __syncthreads();
#pragma unroll
        for (int kk = 0; kk < 16; kk++) {
            float4 a = *(const float4*)&As[kk][ty * 4];
            float4 b = *(const float4*)&Bs[kk][tx * 4];
            float aa[4] = {a.x, a.y, a.z, a.w};
            float bb[4] = {b.x, b.y, b.z, b.w};
#pragma unroll
            for (int i = 0; i < 4; i++)
#pragma unroll
                for (int j = 0; j < 4; j++) acc[i][j] += aa[i] * bb[j];
        }
        __syncthreads();
    }
    const int ncol = n0 + tx * 4;
#pragma unroll
    for (int i = 0; i < 4; i++) {
        int row = m0 + ty * 4 + i;
        float* cp = C + (long)row * N + ncol;
#pragma unroll
        for (int j = 0; j < 4; j++) ATOMIC_ADD_F32(cp + j, acc[i][j]);
    }
}

// scale = g*rsqrt(vr+eps); shift = (b1-mu)*scale + bt; optionally zero worklist cnt
__global__ void k_scale_shift(const float* __restrict__ g, const float* __restrict__ vr,
                              const float* __restrict__ mu, const float* __restrict__ bt,
                              const float* __restrict__ b1,
                              float* __restrict__ scale, float* __restrict__ shift, int n,
                              int* __restrict__ wlc)
{
    int i = blockIdx.x * 256 + threadIdx.x;
    if (wlc && i == 0) *wlc = 0;
    if (i >= n) return;
    float sc = g[i] * rsqrtf(vr[i] + EPSc);
    scale[i] = sc;
    shift[i] = (b1[i] - mu[i]) * sc + bt[i];
}

// ext head: logits (O=2) + softmax + exist reduction. block per (b,nc).
__global__ __launch_bounds__(256) void k_ext_head(
    const float* __restrict__ hbuf, const float* __restrict__ w2, const float* __restrict__ b2,
    float* __restrict__ outExt, int* __restrict__ exist)
{
    __shared__ float red[256];
    const int bc = blockIdx.x;
    const int b = bc / NCc, nc = bc % NCc;
    const int h = threadIdx.x;
    float p0 = 0.f;
    if (h < Hh) {
        const int col = b * Hh + h;
        const float* hp = hbuf + (long)(nc * DSc) * BHc + col;
        const float* w0p = w2 + (nc * 2 + 0) * DSc;
        const float* w1p = w2 + (nc * 2 + 1) * DSc;
        float lg0 = b2[nc * 2 + 0], lg1 = b2[nc * 2 + 1];
        for (int s = 0; s < DSc; s++) {
            float hv = hp[(long)s * BHc];
            lg0 += hv * w0p[s];
            lg1 += hv * w1p[s];
        }
        float mx = fmaxf(lg0, lg1);
        float e0 = expf(lg0 - mx), e1 = expf(lg1 - mx);
        float inv = 1.f / (e0 + e1);
        p0 = e0 * inv;
        float* op = outExt + ((long)bc * Hh + h) * 2;
        op[0] = p0;
        op[1] = e1 * inv;
    }
    red[threadIdx.x] = p0;
    __syncthreads();
    for (int st = 128; st > 0; st >>= 1) {
        if (threadIdx.x < st) red[threadIdx.x] += red[threadIdx.x + st];
        __syncthreads();
    }
    if (threadIdx.x == 0) exist[bc] = (red[0] / Hh > THRc) ? 1 : 0;
}

// ============================================================
// wave-per-column softmax over lgT[nc][col][144]; top-2 gap flagging (stage1)
// ============================================================
__global__ __launch_bounds__(256) void k_softmax2(
    const float* __restrict__ lgT, float* __restrict__ outCls, int* __restrict__ corr,
    int* __restrict__ wlc, int* __restrict__ wl, int stage1)
{
    int wg = blockIdx.x * 4 + (threadIdx.x >> 6);
    int l = threadIdx.x & 63;
    int nc = wg / BHc, col = wg % BHc;
    int b = col / Hh, h = col % Hh;
    const float* p = lgT + ((long)nc * BHc + col) * 144;
    float v0 = p[l];
    float v1 = p[l + 64];
    float v2 = (l < 16) ? p[l + 128] : -1e30f;
    // per-lane top2 (lower idx wins ties)
    float m1 = v0, m2; int i1 = l;
    if (v1 > m1) { m2 = m1; m1 = v1; i1 = l + 64; } else m2 = v1;
    if (v2 > m1) { m2 = m1; m1 = v2; i1 = l + 128; } else m2 = fmaxf(m2, v2);
    // butterfly top2 merge across 64 lanes
#pragma unroll
    for (int off = 32; off; off >>= 1) {
        float o1 = __shfl_xor(m1, off);
        float o2 = __shfl_xor(m2, off);
        int oi = __shfl_xor(i1, off);
        if (o1 > m1 || (o1 == m1 && oi < i1)) { m2 = fmaxf(m1, o2); m1 = o1; i1 = oi; }
        else m2 = fmaxf(m2, o1);
    }
    float e0 = expf(v0 - m1);
    float e1 = expf(v1 - m1);
    float e2 = (l < 16) ? expf(v2 - m1) : 0.f;
    float s = e0 + e1 + e2;
#pragma unroll
    for (int off = 32; off; off >>= 1) s += __shfl_xor(s, off);
    float inv = 1.f / s;
    int row = (b * NCc + nc) * Hh + h;
    float* op = outCls + (long)row * 144;
    op[l] = e0 * inv;
    op[l + 64] = e1 * inv;
    if (l < 16) op[l + 128] = e2 * inv;
    if (l == 0) {
        corr[row] = i1;
        if (stage1 && (m1 - m2) < GAPDELTA) {
            int ix = atomicAdd(wlc, 1);
            if (ix < WLCAP) wl[ix] = wg;
        }
    }
}

// ============================================================
// exact fp32 recompute for flagged columns: h = BN(X@w1), logits, argmax, softmax
// ============================================================
__global__ __launch_bounds__(256) void k_fixup(
    const float* __restrict__ x, const float* __restrict__ w1,
    const float* __restrict__ w2, const float* __restrict__ b2,
    const float* __restrict__ scale, const float* __restrict__ shift,
    const int* __restrict__ wlc, const int* __restrict__ wl,
    float* __restrict__ outCls, int* __restrict__ corr)
{
    __shared__ float hs[512];
    __shared__ float lg[144];
    __shared__ float mx_s, sum_s;
    __shared__ int bi_s;
    int cnt = min(*wlc, WLCAP);
    for (int it = blockIdx.x; it < cnt; it += gridDim.x) {
        int code = wl[it];
        int nc = code / BHc, col = code % BHc;
        int b = col / Hh, h = col % Hh;
        for (int s = threadIdx.x; s < 512; s += 256) {
            const float* wp = w1 + ((long)(nc * 512 + s)) * CINc;
            float d = 0.f;
            for (int f = 0; f < DFc; f++) {
                const float* xp = x + ((long)(b * DFc + f) * Hh + h) * Ww;
                const float* wq = wp + f * Ww;
                for (int w = 0; w < Ww; w++) d += xp[w] * wq[w];
            }
            hs[s] = d * scale[nc * 512 + s] + shift[nc * 512 + s];
        }
        __syncthreads();
        if (threadIdx.x < 144) {
            const float* wp2 = w2 + ((long)(nc * 144 + threadIdx.x)) * 512;
            float d = b2[nc * 144 + threadIdx.x];
            for (int s = 0; s < 512; s++) d += hs[s] * wp2[s];
            lg[threadIdx.x] = d;
        }
        __syncthreads();
        if (threadIdx.x == 0) {
            float mx = lg[0]; int bi = 0;
            for (int o = 1; o < 144; o++) if (lg[o] > mx) { mx = lg[o]; bi = o; }
            float sm = 0.f;
            for (int o = 0; o < 144; o++) sm += expf(lg[o] - mx);
            mx_s = mx; sum_s = sm; bi_s = bi;
        }
        __syncthreads();
        int row = (b * NCc + nc) * Hh + h;
        if (threadIdx.x < 144)
            outCls[(long)row * 144 + threadIdx.x] = expf(lg[threadIdx.x] - mx_s) / sum_s;
        if (threadIdx.x == 0) corr[row] = bi_s;
        __syncthreads();
    }
}

// gather window: win[(b*NC+nc)][f*H*K + h*K + k]
__global__ void k_gather(const float* __restrict__ x, const int* __restrict__ corr,
                         float* __restrict__ win)
{
    int tid = blockIdx.x * 256 + threadIdx.x;
    if (tid >= Bb * NCc * ITCc) return;
    int row = tid / ITCc, i = tid % ITCc;
    int b = row / NCc, nc = row % NCc;
    int f = i / (Hh * KWc);
    int r = i % (Hh * KWc);
    int h = r / KWc, k = r % KWc;
    int j = corr[(b * NCc + nc) * Hh + h] + k - OFFc;
    float v = 0.f;
    if (j >= 0 && j < Ww) v = x[((long)(b * DFc + f) * Hh + h) * Ww + j];
    win[tid] = v;
}

__global__ __launch_bounds__(256) void k_layernorm(
    const float* __restrict__ in, const float* __restrict__ g,
    const float* __restrict__ bta, float* __restrict__ out)
{
    __shared__ float r1[256], r2[256];
    const int row = blockIdx.x;
    const int t = threadIdx.x;
    const float* p = in + (long)row * DTc;
    float s = 0.f, sq = 0.f;
    for (int i = t; i < DTc; i += 256) {
        float v = p[i];
        s += v; sq += v * v;
    }
    r1[t] = s; r2[t] = sq;
    __syncthreads();
    for (int st = 128; st > 0; st >>= 1) {
        if (t < st) { r1[t] += r1[t + st]; r2[t] += r2[t + st]; }
        __syncthreads();
    }
    float mean = r1[0] / DTc;
    float var = r2[0] / DTc - mean * mean;
    float rstd = rsqrtf(var + EPSc);
    float* o = out + (long)row * DTc;
    for (int i = t; i < DTc; i += 256) o[i] = (p[i] - mean) * rstd * g[i] + bta[i];
}

// tiny attention: one thread per (b, head, n)
__global__ void k_attention(const float* __restrict__ qkv, const int* __restrict__ exist,
                            float* __restrict__ obuf)
{
    int idx = blockIdx.x * 256 + threadIdx.x;
    if (idx >= Bb * HEADSc * NCc) return;
    int b = idx / (HEADSc * NCc);
    int r = idx % (HEADSc * NCc);
    int hd = r / NCc, n = r % NCc;
    const float* base = qkv + (long)b * NCc * (3 * INNERc);
    const float* q = base + (long)n * (3 * INNERc) + hd * DHc;
    float s[NCc];
    for (int m = 0; m < NCc; m++) {
        const float* kp = base + (long)m * (3 * INNERc) + INNERc + hd * DHc;
        float d = 0.f;
        for (int t = 0; t < DHc; t++) d += q[t] * kp[t];
        s[m] = exist[b * NCc + m] ? d * 0.125f : -1e9f;
    }
    float mx = s[0];
    for (int m = 1; m < NCc; m++) mx = fmaxf(mx, s[m]);
    float sum = 0.f;
    for (int m = 0; m < NCc; m++) { s[m] = expf(s[m] - mx); sum += s[m]; }
    float inv = 1.f / sum;
    for (int m = 0; m < NCc; m++) s[m] *= inv;
    float* op = obuf + (long)(b * NCc + n) * INNERc + hd * DHc;
    for (int t = 0; t < DHc; t++) {
        float acc = 0.f;
        for (int m = 0; m < NCc; m++)
            acc += s[m] * base[(long)m * (3 * INNERc) + 2 * INNERc + hd * DHc + t];
        op[t] = acc;
    }
}

__global__ void k_gelu(float* __restrict__ p, int n)
{
    int tid = blockIdx.x * 256 + threadIdx.x;
    if (tid < n) {
        float v = p[tid];
        p[tid] = 0.5f * v * (1.f + erff(v * 0.70710678118654752440f));
    }
}

__global__ void k_copy4(const float4* __restrict__ s, float4* __restrict__ d, int n)
{
    int tid = blockIdx.x * 256 + threadIdx.x;
    if (tid < n) d[tid] = s[tid];
}

// scatter dec into x2; per-(b,h,f) thread, c descending, first-writer-wins per column
__global__ void k_scatter(const float* __restrict__ dec, const int* __restrict__ corr,
                          const int* __restrict__ exist, float* __restrict__ x2)
{
    int idx = blockIdx.x * 256 + threadIdx.x;
    if (idx >= Bb * Hh * DFc) return;
    int b = idx / (Hh * DFc);
    int r = idx % (Hh * DFc);
    int h = r / DFc, f = r % DFc;
    if (h >= Hh - 1) return;  // hmask
    unsigned long long m0 = 0ull, m1 = 0ull, m2 = 0ull;
    float* xrow = x2 + ((long)(b * DFc + f) * Hh + h) * Ww;
    for (int c = NCc - 1; c >= 0; c--) {
        if (!exist[b * NCc + c]) continue;
        int cr = corr[(b * NCc + c) * Hh + h];
        const float* dp = dec + (long)(b * NCc + c) * ITCc + f * (Hh * KWc) + h * KWc;
        for (int k = 0; k < KWc; k++) {
            int j = cr + k - OFFc;
            if (j < 0 || j >= Ww) continue;
            bool seen;
            if (j < 64) { unsigned long long bit = 1ull << j; seen = (m0 & bit) != 0; m0 |= bit; }
            else if (j < 128) { unsigned long long bit = 1ull << (j - 64); seen = (m1 & bit) != 0; m1 |= bit; }
            else { unsigned long long bit = 1ull << (j - 128); seen = (m2 & bit) != 0; m2 |= bit; }
            if (!seen) xrow[j] = dp[k];
        }
    }
}

extern "C" void kernel_launch(void* const* d_in, const int* in_sizes, int n_in,
                              void* d_out, int out_size, void* d_ws, size_t ws_size,
                              hipStream_t stream)
{
    const float* const* in = (const float* const*)d_in;
    const float* x = in[0];
    // input index bases: ext=1, cls=9, ext2=17, cls2=25
    const float* emb = in[33];
    const float* tok_w = in[34]; const float* tok_b = in[35];
    const float* ln1_g = in[36]; const float* ln1_b = in[37];
    const float* qkv_w = in[38];
    const float* out_w = in[39]; const float* out_b = in[40];
    const float* ln2_g = in[41]; const float* ln2_b = in[42];
    const float* ff_w1 = in[43]; const float* ff_b1 = in[44];
    const float* ff_w2 = in[45]; const float* ff_b2 = in[46];
    const float* lnf_g = in[47]; const float* lnf_b = in[48];
    const float* dec_w = in[49]; const float* dec_b = in[50];

    float* out = (float*)d_out;
    float* outExt1 = out;
    float* outCls1 = out + 55296;
    float* outExt2 = out + 4036608;
    float* outCls2 = out + 4091904;

    // ---- workspace layout (floats) ----
    const long strideA  = (long)NCc * DSc * CINc;   // 3,538,944 bf16 / plane (w1)
    const long strideA2 = (long)NCc * 256 * 512;    //   786,432 bf16 / plane (w2 padded)
    const long strideB  = (long)BHc * CINc;         // 5,308,416 bf16 / plane (x)
    const long strideH  = (long)NCc * BHc * DSc;    // 14,155,776 bf16 / plane (h)
    float* ws = (float*)d_ws;
    float* hbuf = ws;                                    // 14,155,776 f (ext h fp32)
    unsigned short* hpl = (unsigned short*)ws;           // alias: 2 h planes (same bytes)
    float* x2 = hbuf;                                    // alias: first 5,308,416 f
    unsigned short* Apl  = (unsigned short*)(ws + 14155776);   // 2 planes w1
    unsigned short* Apl2 = (unsigned short*)(ws + 17694720);   // 2 planes w2 padded
    unsigned short* Bpl  = (unsigned short*)(ws + 18481152);   // 2 planes x
    float* lgT  = ws + 18481152;                         // alias over Bpl (3,981,312 f)
    float* windec = ws + 18481152;                       // alias over Bpl
    float* tok  = windec + 1105920;
    float* ybuf = tok + 196608;
    float* qkvB = ybuf + 196608;
    float* obuf = qkvB + 589824;
    float* ffh  = obuf + 196608;
    float* scaleB = ws + 26443776;
    float* shiftB = scaleB + 3072;
    int* corrB  = (int*)(shiftB + 3072);                 // 27648
    int* existB = corrB + 27648;                         // 192
    int* wlcB   = existB + 192;
    int* wlB    = wlcB + 1;                              // WLCAP
    float* win = windec;
    float* dec = windec;

    auto run_stage = [&](int be, int bc, float* oExt, float* oCls, bool stage1) {
        // ext head (mode 0: fp32 h)
        k_scale_shift<<<12, 256, 0, stream>>>(in[be + 2], in[be + 5], in[be + 4],
                                              in[be + 3], in[be + 1], scaleB, shiftB,
                                              NCc * DSc, nullptr);
        k_split_w<<<13824, 256, 0, stream>>>(in[be + 0], Apl, strideA, NCc * DSc * CINc);
        gemm_mfma<2, 3, 0><<<dim3(36, 24), 256, 0, stream>>>(Apl, strideA, Bpl, strideB,
                                                             hbuf, NCc * DSc, BHc, CINc,
                                                             scaleB, shiftB);
        k_ext_head<<<Bb * NCc, 256, 0, stream>>>(hbuf, in[be + 6], in[be + 7], oExt, existB);
        // cls head (mode 1: bf16 h planes), then MFMA 2nd GEMM + softmax
        k_scale_shift<<<12, 256, 0, stream>>>(in[bc + 2], in[bc + 5], in[bc + 4],
                                              in[bc + 3], in[bc + 1], scaleB, shiftB,
                                              NCc * DSc, wlcB);
        k_split_w<<<13824, 256, 0, stream>>>(in[bc + 0], Apl, strideA, NCc * DSc * CINc);
        gemm_mfma<2, 3, 1><<<dim3(36, 24), 256, 0, stream>>>(Apl, strideA, Bpl, strideB,
                                                             (void*)hpl, NCc * DSc, BHc, CINc,
                                                             scaleB, shiftB);
        k_split_w2<<<3072, 256, 0, stream>>>(in[bc + 6], Apl2, strideA2);
        gemm_cls2<<<dim3(36, 2, NCc), 256, 0, stream>>>(Apl2, strideA2, hpl, strideH,
                                                        lgT, in[bc + 7]);
        k_softmax2<<<6912, 256, 0, stream>>>(lgT, oCls, corrB, wlcB, wlB, stage1 ? 1 : 0);
        if (stage1)
            k_fixup<<<192, 256, 0, stream>>>(x, in[bc + 0], in[bc + 6], in[bc + 7],
                                             scaleB, shiftB, wlcB, wlB, oCls, corrB);
    };

    // ======== stage 1 ========
    k_split_x<<<20736, 256, 0, stream>>>(x, Bpl, strideB);
    run_stage(1, 9, outExt1, outCls1, true);

    // gather + token projection (win clobbers lgT — both dead by now)
    k_gather<<<4320, 256, 0, stream>>>(x, corrB, win);
    k_tok_init<<<768, 256, 0, stream>>>(tok, tok_b, emb);
    gemm_nt_sk<<<dim3(16, 3, 8), 256, 0, stream>>>(win, tok_w, tok, 192, DTc, ITCc, 720);

    // transformer block
    k_layernorm<<<192, 256, 0, stream>>>(tok, ln1_g, ln1_b, ybuf);
    k_bias<<<2304, 256, 0, stream>>>(qkvB, nullptr, 192, 3 * INNERc, 0);
    gemm_nt_sk<<<dim3(48, 3, 4), 256, 0, stream>>>(ybuf, qkv_w, qkvB, 192, 3 * INNERc, DTc, 256);
    k_attention<<<12, 256, 0, stream>>>(qkvB, existB, obuf);
    k_bias<<<768, 256, 0, stream>>>(tok, out_b, 192, DTc, 1);
    gemm_nt_sk<<<dim3(16, 3, 8), 256, 0, stream>>>(obuf, out_w, tok, 192, DTc, INNERc, 128);
    k_layernorm<<<192, 256, 0, stream>>>(tok, ln2_g, ln2_b, ybuf);
    k_bias<<<1536, 256, 0, stream>>>(ffh, ff_b1, 192, MLPc, 0);
    gemm_nt_sk<<<dim3(32, 3, 4), 256, 0, stream>>>(ybuf, ff_w1, ffh, 192, MLPc, DTc, 256);
    k_gelu<<<1536, 256, 0, stream>>>(ffh, 192 * MLPc);
    k_bias<<<768, 256, 0, stream>>>(tok, ff_b2, 192, DTc, 1);
    gemm_nt_sk<<<dim3(16, 3, 8), 256, 0, stream>>>(ffh, ff_w2, tok, 192, DTc, MLPc, 256);
    k_layernorm<<<192, 256, 0, stream>>>(tok, lnf_g, lnf_b, ybuf);
    k_bias<<<4320, 256, 0, stream>>>(dec, dec_b, 192, ITCc, 0);
    gemm_nt_sk<<<dim3(90, 3, 2), 256, 0, stream>>>(ybuf, dec_w, dec, 192, ITCc, DTc, 512);

    // scatter into x2 (copy of x); x2 aliases hbuf (stage-1 h data dead)
    k_copy4<<<5184, 256, 0, stream>>>((const float4*)x, (float4*)x2, 1327104);
    k_scatter<<<144, 256, 0, stream>>>(dec, corrB, existB, x2);

    // ======== stage 2 ======== (dec consumed; Bpl overwrite is safe)
    k_split_x<<<20736, 256, 0, stream>>>(x2, Bpl, strideB);
    run_stage(17, 25, outExt2, outCls2, false);

    (void)in_sizes; (void)n_in; (void)out_size; (void)ws_size;
}